// Round 2
// baseline (5388.515 us; speedup 1.0000x reference)
//
#include <hip/hip_runtime.h>

#define H 32
#define FIN 64
#define BNODES 256      // nodes per bucket (dst_local fits 8 bits)
#define NBMAX 1024      // max buckets (N <= 262144)
#define CHUNK 4096      // edges per scatter block

// ---------------- degree histogram ----------------

__global__ void k_hist(const int* __restrict__ dst, int* __restrict__ deg, int E) {
    int e = blockIdx.x * blockDim.x + threadIdx.x;
    if (e < E) atomicAdd(&deg[dst[e]], 1);
}

// bucket counts: bcnt[b] = sum of deg over its 256 nodes
__global__ void k_bucket_cnt(const int* __restrict__ deg, int* __restrict__ bcnt, int n) {
    __shared__ int s[256];
    int node = blockIdx.x * BNODES + threadIdx.x;
    s[threadIdx.x] = (node < n) ? deg[node] : 0;
    __syncthreads();
    for (int st = 128; st > 0; st >>= 1) {
        if (threadIdx.x < st) s[threadIdx.x] += s[threadIdx.x + st];
        __syncthreads();
    }
    if (threadIdx.x == 0) bcnt[blockIdx.x] = s[0];
}

// single-block exclusive scan of bucket counts (NB <= 1024)
__global__ void k_scanb(const int* __restrict__ bcnt, int* __restrict__ boff,
                        int* __restrict__ gcur, int NB) {
    __shared__ int wsum[16];
    __shared__ int wbase[17];
    int tid = threadIdx.x, lane = tid & 63, wid = tid >> 6;
    int v = (tid < NB) ? bcnt[tid] : 0;
    int incl = v;
    #pragma unroll
    for (int d = 1; d < 64; d <<= 1) {
        int t = __shfl_up(incl, d, 64);
        if (lane >= d) incl += t;
    }
    if (lane == 63) wsum[wid] = incl;
    __syncthreads();
    if (tid == 0) {
        int a = 0;
        #pragma unroll
        for (int w = 0; w < 16; ++w) { wbase[w] = a; a += wsum[w]; }
        wbase[16] = a;
    }
    __syncthreads();
    int excl = wbase[wid] + incl - v;
    if (tid < NB) { boff[tid] = excl; gcur[tid] = excl; }
    if (tid == 0) boff[NB] = wbase[16];
}

__global__ void k_dinv(const int* __restrict__ deg, float* __restrict__ dinv, int n) {
    int i = blockIdx.x * blockDim.x + threadIdx.x;
    if (i < n) dinv[i] = rsqrtf((float)(deg[i] + 1));
}

// ---------------- bucket scatter ----------------
// record = (src << 8) | (dst & 255); bucket = dst >> 8

__global__ void k_scatter(const int* __restrict__ src, const int* __restrict__ dst,
                          int* __restrict__ gcur, int* __restrict__ barr, int E, int NB) {
    __shared__ int lcnt[NBMAX];
    __shared__ int lbase[NBMAX];
    __shared__ int recs[CHUNK];
    __shared__ unsigned short rnk[CHUNK];
    __shared__ unsigned short bkt[CHUNK];
    int tid = threadIdx.x;
    for (int i = tid; i < NB; i += 256) lcnt[i] = 0;
    __syncthreads();
    int base = blockIdx.x * CHUNK;
    for (int i = tid; i < CHUNK; i += 256) {
        int e = base + i;
        if (e < E) {
            int d = dst[e];
            int b = d >> 8;
            recs[i] = (src[e] << 8) | (d & 255);
            bkt[i] = (unsigned short)b;
            rnk[i] = (unsigned short)atomicAdd(&lcnt[b], 1);
        }
    }
    __syncthreads();
    for (int b = tid; b < NB; b += 256) {
        int c = lcnt[b];
        lbase[b] = c ? atomicAdd(&gcur[b], c) : 0;
    }
    __syncthreads();
    for (int i = tid; i < CHUNK; i += 256) {
        int e = base + i;
        if (e < E) barr[lbase[bkt[i]] + rnk[i]] = recs[i];
    }
}

// ---------------- dense node transforms ----------------

// xwp = (x @ W_gcn) * dinv   (x: [n,64], W: [64,32])
__global__ void k_gemm64s(const float* __restrict__ x, const float* __restrict__ W,
                          const float* __restrict__ dinv, float* __restrict__ xwp, int n) {
    __shared__ float Ws[FIN * H];
    __shared__ float xs[8 * FIN];
    int tid = threadIdx.x;
    for (int i = tid; i < FIN * H; i += 256) Ws[i] = W[i];
    int nodeBase = blockIdx.x * 8;
    for (int i = tid; i < 8 * FIN; i += 256) {
        int node = nodeBase + i / FIN;
        xs[i] = (node < n) ? x[(size_t)node * FIN + (i & 63)] : 0.f;
    }
    __syncthreads();
    int nl = tid >> 5, f = tid & 31;
    int node = nodeBase + nl;
    if (node < n) {
        float acc = 0.f;
        #pragma unroll
        for (int ff = 0; ff < FIN; ++ff) acc += xs[nl * FIN + ff] * Ws[ff * H + f];
        xwp[(size_t)node * H + f] = acc * dinv[node];
    }
}

// GCN via buckets: h = relu( dinv[g]*(sum_{s->g} xwp[s] + xwp[g]) + b )
__global__ void k_gcn_b(const float* __restrict__ xwp, const int* __restrict__ boff,
                        const int* __restrict__ barr, const float* __restrict__ dinv,
                        const float* __restrict__ bias, float* __restrict__ h, int n) {
    __shared__ float acc[BNODES * H];   // 32 KB
    int tid = threadIdx.x;
    for (int i = tid; i < BNODES * H; i += 256) acc[i] = 0.f;
    __syncthreads();
    int bk = blockIdx.x;
    int e0 = boff[bk], e1 = boff[bk + 1];
    int f = tid & 31, slot = tid >> 5;
    for (int e = e0 + slot; e < e1; e += 8) {
        int rec = barr[e];
        int s = rec >> 8, dl = rec & 255;
        atomicAdd(&acc[dl * H + f], xwp[(size_t)s * H + f]);
    }
    __syncthreads();
    int gbase = bk * BNODES;
    for (int l = slot; l < BNODES; l += 8) {
        int g = gbase + l;
        if (g < n) {
            float di = dinv[g];
            float out = di * (acc[l * H + f] + xwp[(size_t)g * H + f]) + bias[f];
            h[(size_t)g * H + f] = fmaxf(out, 0.f);
        }
    }
}

// SAGE via buckets: hout = relu( (sum/max(cnt,1)) @ Wl + bl + hin[g] @ Wr )
__global__ void k_sage_b(const float* __restrict__ hin, const int* __restrict__ boff,
                         const int* __restrict__ barr, const int* __restrict__ deg,
                         const float* __restrict__ Wl, const float* __restrict__ bl,
                         const float* __restrict__ Wr, float* __restrict__ hout, int n) {
    __shared__ float acc[BNODES * H];   // 32 KB
    __shared__ float Wls[H * H], Wrs[H * H];
    int tid = threadIdx.x;
    for (int i = tid; i < H * H; i += 256) { Wls[i] = Wl[i]; Wrs[i] = Wr[i]; }
    for (int i = tid; i < BNODES * H; i += 256) acc[i] = 0.f;
    __syncthreads();
    int bk = blockIdx.x;
    int e0 = boff[bk], e1 = boff[bk + 1];
    int f = tid & 31, slot = tid >> 5;
    for (int e = e0 + slot; e < e1; e += 8) {
        int rec = barr[e];
        int s = rec >> 8, dl = rec & 255;
        atomicAdd(&acc[dl * H + f], hin[(size_t)s * H + f]);
    }
    __syncthreads();
    int gbase = bk * BNODES;
    for (int l = slot; l < BNODES; l += 8) {
        int g = gbase + l;
        if (g < n) {
            float inv = 1.f / fmaxf((float)deg[g], 1.f);
            float hf = hin[(size_t)g * H + f];
            float o = bl[f];
            #pragma unroll
            for (int ff = 0; ff < H; ++ff) {
                float mv = acc[l * H + ff] * inv;     // LDS broadcast
                float hv = __shfl(hf, ff, 32);
                o += mv * Wls[ff * H + f] + hv * Wrs[ff * H + f];
            }
            hout[(size_t)g * H + f] = fmaxf(o, 0.f);
        }
    }
}

// ---------------- attention pooling ----------------

__global__ void k_poolsum(const float* __restrict__ rep, const int* __restrict__ batch,
                          float* __restrict__ sums, float* __restrict__ cntg, int n) {
    int g = (blockIdx.x * blockDim.x + threadIdx.x) >> 5;
    int f = threadIdx.x & 31;
    if (g >= n) return;
    int b = batch[g];
    atomicAdd(&sums[b * H + f], rep[(size_t)g * H + f]);
    if (f == 0) atomicAdd(&cntg[b], 1.f);
}

__global__ void k_ctx(const float* __restrict__ sums, const float* __restrict__ cntg,
                      const float* __restrict__ wc, float* __restrict__ ctx, int Bn) {
    int idx = blockIdx.x * blockDim.x + threadIdx.x;
    if (idx >= Bn * H) return;
    int b = idx >> 5, f = idx & 31;
    float inv = 1.f / fmaxf(cntg[b], 1.f);
    float acc = 0.f;
    #pragma unroll
    for (int ff = 0; ff < H; ++ff) acc += sums[b * H + ff] * inv * wc[ff * H + f];
    ctx[idx] = tanhf(acc);
}

__global__ void k_gatepool(const float* __restrict__ rep, const int* __restrict__ batch,
                           const float* __restrict__ ctx, float* __restrict__ pooled, int n) {
    int g = (blockIdx.x * blockDim.x + threadIdx.x) >> 5;
    int f = threadIdx.x & 31;
    if (g >= n) return;
    int b = batch[g];
    float r = rep[(size_t)g * H + f];
    float d = r * ctx[b * H + f];
    #pragma unroll
    for (int m = 16; m >= 1; m >>= 1) d += __shfl_xor(d, m, 32);
    float gate = 1.f / (1.f + expf(-d));
    atomicAdd(&pooled[b * H + f], gate * r);
}

// ---------------- NTN + final MLP ----------------

__global__ void k_ntn(const float* __restrict__ hi, const float* __restrict__ hj,
                      const float* __restrict__ Wntn, const float* __restrict__ Vntn,
                      const float* __restrict__ bntn, const float* __restrict__ mlpw,
                      const float* __restrict__ mlpb, float* __restrict__ out, int Bn) {
    __shared__ float his[8 * H], hjs[8 * H];
    int tid = threadIdx.x;
    int bb = blockIdx.x * 8;
    for (int i = tid; i < 8 * H; i += 256) {
        int b = bb + i / H;
        his[i] = (b < Bn) ? hi[b * H + (i & 31)] : 0.f;
        hjs[i] = (b < Bn) ? hj[b * H + (i & 31)] : 0.f;
    }
    __syncthreads();
    int bl = tid >> 5, k = tid & 31;
    int b = bb + bl;
    if (b >= Bn) return;
    const float* W = Wntn + k * H * H;
    float g = bntn[k];
    #pragma unroll 4
    for (int i = 0; i < H; ++i) {
        float acc = 0.f;
        #pragma unroll
        for (int j = 0; j < H; ++j) acc += W[i * H + j] * hjs[bl * H + j];
        g += his[bl * H + i] * acc;
    }
    const float* V = Vntn + k * 2 * H;
    #pragma unroll
    for (int f = 0; f < H; ++f) g += his[bl * H + f] * V[f] + hjs[bl * H + f] * V[H + f];
    float sc = g * mlpw[k];
    #pragma unroll
    for (int m = 16; m >= 1; m >>= 1) sc += __shfl_xor(sc, m, 32);
    if (k == 0) out[b] = sc + mlpb[0];
}

// ---------------- host orchestration ----------------

extern "C" void kernel_launch(void* const* d_in, const int* in_sizes, int n_in,
                              void* d_out, int out_size, void* d_ws, size_t ws_size,
                              hipStream_t stream) {
    const float* x_i      = (const float*)d_in[0];
    const int*   ei_i     = (const int*)d_in[1];
    const int*   batch_i  = (const int*)d_in[2];
    const float* x_j      = (const float*)d_in[3];
    const int*   ei_j     = (const int*)d_in[4];
    const int*   batch_j  = (const int*)d_in[5];
    const float* W_gcn    = (const float*)d_in[6];
    const float* b_gcn    = (const float*)d_in[7];
    const float* sage_l   = (const float*)d_in[8];
    const float* sage_bl  = (const float*)d_in[9];
    const float* sage_r   = (const float*)d_in[10];
    const float* weight_c = (const float*)d_in[11];
    const float* W_ntn    = (const float*)d_in[12];
    const float* V_ntn    = (const float*)d_in[13];
    const float* b_ntn    = (const float*)d_in[14];
    const float* mlp_w    = (const float*)d_in[15];
    const float* mlp_b    = (const float*)d_in[16];

    const int N = in_sizes[0] / FIN;
    const int E = in_sizes[1] / 2;
    const int B = out_size;
    const int NB = (N + BNODES - 1) / BNODES;   // 391 for N=100000

    char* p = (char*)d_ws;
    auto alloc = [&](size_t bytes) {
        char* r = p;
        p += (bytes + 255) & ~(size_t)255;
        return r;
    };
    int*   deg      = (int*)alloc((size_t)N * 4);
    float* dinv     = (float*)alloc((size_t)N * 4);
    int*   bcnt     = (int*)alloc((size_t)NB * 4);
    int*   boff     = (int*)alloc((size_t)(NB + 1) * 4);
    int*   gcur     = (int*)alloc((size_t)NB * 4);
    int*   barr     = (int*)alloc((size_t)E * 4);
    float* h0       = (float*)alloc((size_t)N * H * 4);
    float* h1       = (float*)alloc((size_t)N * H * 4);
    float* sums     = (float*)alloc((size_t)B * H * 4);
    float* cntg     = (float*)alloc((size_t)B * 4);
    float* ctx      = (float*)alloc((size_t)B * H * 4);
    float* pooled_i = (float*)alloc((size_t)B * H * 4);
    float* pooled_j = (float*)alloc((size_t)B * H * 4);

    const int nodeBlocks = (N * 32 + 255) / 256;

    for (int gi = 0; gi < 2; ++gi) {
        const float* x     = gi ? x_j : x_i;
        const int*   ei    = gi ? ei_j : ei_i;
        const int*   batch = gi ? batch_j : batch_i;
        float* pooled      = gi ? pooled_j : pooled_i;
        const int* src = ei;
        const int* dst = ei + E;

        hipMemsetAsync(deg, 0, (size_t)N * 4, stream);
        k_hist<<<(E + 255) / 256, 256, 0, stream>>>(dst, deg, E);
        k_bucket_cnt<<<NB, 256, 0, stream>>>(deg, bcnt, N);
        k_scanb<<<1, 1024, 0, stream>>>(bcnt, boff, gcur, NB);
        k_dinv<<<(N + 255) / 256, 256, 0, stream>>>(deg, dinv, N);
        k_scatter<<<(E + CHUNK - 1) / CHUNK, 256, 0, stream>>>(src, dst, gcur, barr, E, NB);

        k_gemm64s<<<(N + 7) / 8, 256, 0, stream>>>(x, W_gcn, dinv, h0, N);
        k_gcn_b<<<NB, 256, 0, stream>>>(h0, boff, barr, dinv, b_gcn, h1, N);
        k_sage_b<<<NB, 256, 0, stream>>>(h1, boff, barr, deg, sage_l, sage_bl, sage_r, h0, N);
        k_sage_b<<<NB, 256, 0, stream>>>(h0, boff, barr, deg, sage_l + H * H, sage_bl + H,
                                         sage_r + H * H, h1, N);

        hipMemsetAsync(sums, 0, (size_t)B * H * 4, stream);
        hipMemsetAsync(cntg, 0, (size_t)B * 4, stream);
        hipMemsetAsync(pooled, 0, (size_t)B * H * 4, stream);
        k_poolsum<<<nodeBlocks, 256, 0, stream>>>(h1, batch, sums, cntg, N);
        k_ctx<<<(B * H + 255) / 256, 256, 0, stream>>>(sums, cntg, weight_c, ctx, B);
        k_gatepool<<<nodeBlocks, 256, 0, stream>>>(h1, batch, ctx, pooled, N);
    }

    k_ntn<<<(B + 7) / 8, 256, 0, stream>>>(pooled_i, pooled_j, W_ntn, V_ntn, b_ntn,
                                           mlp_w, mlp_b, (float*)d_out, B);
}

// Round 4
// 1613.809 us; speedup vs baseline: 3.3390x; 3.3390x over previous
//
#include <hip/hip_runtime.h>

#define H 32
#define FIN 64
#define BNODES 256      // nodes per bucket (dst_local fits 8 bits)
#define NBMAX 512       // max buckets
#define CHUNK 4096      // edges per scatter block

// ---------------- degree histogram ----------------

__global__ void k_hist(const int* __restrict__ dst, int* __restrict__ deg, int E) {
    int e = blockIdx.x * blockDim.x + threadIdx.x;
    if (e < E) atomicAdd(&deg[dst[e]], 1);
}

// bucket counts of PADDED degrees: bcnt[b] = sum over nodes of (deg+3)&~3
__global__ void k_bucket_cnt(const int* __restrict__ deg, int* __restrict__ bcnt, int n) {
    __shared__ int s[256];
    int node = blockIdx.x * BNODES + threadIdx.x;
    int d = (node < n) ? deg[node] : 0;
    s[threadIdx.x] = (d + 3) & ~3;
    __syncthreads();
    for (int st = 128; st > 0; st >>= 1) {
        if (threadIdx.x < st) s[threadIdx.x] += s[threadIdx.x + st];
        __syncthreads();
    }
    if (threadIdx.x == 0) bcnt[blockIdx.x] = s[0];
}

// single-block exclusive scan of bucket counts (NB <= 1024); also offs[n] = total
__global__ void k_scanb(const int* __restrict__ bcnt, int* __restrict__ boff,
                        int* __restrict__ gcur, int* __restrict__ offs, int NB, int n) {
    __shared__ int wsum[16];
    __shared__ int wbase[17];
    int tid = threadIdx.x, lane = tid & 63, wid = tid >> 6;
    int v = (tid < NB) ? bcnt[tid] : 0;
    int incl = v;
    #pragma unroll
    for (int d = 1; d < 64; d <<= 1) {
        int t = __shfl_up(incl, d, 64);
        if (lane >= d) incl += t;
    }
    if (lane == 63) wsum[wid] = incl;
    __syncthreads();
    if (tid == 0) {
        int a = 0;
        #pragma unroll
        for (int w = 0; w < 16; ++w) { wbase[w] = a; a += wsum[w]; }
        wbase[16] = a;
    }
    __syncthreads();
    int excl = wbase[wid] + incl - v;
    if (tid < NB) { boff[tid] = excl; gcur[tid] = excl; }
    if (tid == 0) { boff[NB] = wbase[16]; offs[n] = wbase[16]; }
}

// per-bucket: node offsets (padded-degree local scan + bucket base), dinv
__global__ void k_offs(const int* __restrict__ deg, const int* __restrict__ boff,
                       int* __restrict__ offs, float* __restrict__ dinv, int n) {
    __shared__ int wsum[4];
    __shared__ int wbase[4];
    int tid = threadIdx.x, lane = tid & 63, wid = tid >> 6;
    int node = blockIdx.x * BNODES + tid;
    int d = (node < n) ? deg[node] : 0;
    int dp = (d + 3) & ~3;
    int incl = dp;
    #pragma unroll
    for (int s = 1; s < 64; s <<= 1) {
        int t = __shfl_up(incl, s, 64);
        if (lane >= s) incl += t;
    }
    if (lane == 63) wsum[wid] = incl;
    __syncthreads();
    if (tid == 0) {
        int a = 0;
        #pragma unroll
        for (int w = 0; w < 4; ++w) { wbase[w] = a; a += wsum[w]; }
    }
    __syncthreads();
    if (node < n) {
        offs[node] = boff[blockIdx.x] + wbase[wid] + incl - dp;
        dinv[node] = rsqrtf((float)(d + 1));
    }
}

// ---------------- bucket scatter ----------------
// record = (src << 8) | (dst & 255); bucket = dst >> 8

__global__ void k_scatter(const int* __restrict__ src, const int* __restrict__ dst,
                          int* __restrict__ gcur, int* __restrict__ barr, int E, int NB) {
    __shared__ int lcnt[NBMAX];
    __shared__ int lbase[NBMAX];
    __shared__ int recs[CHUNK];
    __shared__ unsigned short rnk[CHUNK];
    __shared__ unsigned short bkt[CHUNK];
    int tid = threadIdx.x;
    for (int i = tid; i < NB; i += 256) lcnt[i] = 0;
    __syncthreads();
    int base = blockIdx.x * CHUNK;
    for (int i = tid; i < CHUNK; i += 256) {
        int e = base + i;
        if (e < E) {
            int d = dst[e];
            int b = d >> 8;
            recs[i] = (src[e] << 8) | (d & 255);
            bkt[i] = (unsigned short)b;
            rnk[i] = (unsigned short)atomicAdd(&lcnt[b], 1);
        }
    }
    __syncthreads();
    for (int b = tid; b < NB; b += 256) {
        int c = lcnt[b];
        lbase[b] = c ? atomicAdd(&gcur[b], c) : 0;
    }
    __syncthreads();
    for (int i = tid; i < CHUNK; i += 256) {
        int e = base + i;
        if (e < E) barr[lbase[bkt[i]] + rnk[i]] = recs[i];
    }
}

// per-bucket sort into exact padded CSR; pad tails with sentinel node n
__global__ void k_sort(const int* __restrict__ barr, const int* __restrict__ boff,
                       const int* __restrict__ gend, const int* __restrict__ offs,
                       int* __restrict__ csr, int n) {
    __shared__ int lcnt[BNODES];
    int tid = threadIdx.x;
    int bk = blockIdx.x;
    lcnt[tid] = 0;
    __syncthreads();
    int e0 = boff[bk], e1 = gend[bk];
    int gbase = bk * BNODES;
    for (int e = e0 + tid; e < e1; e += 256) {
        int rec = barr[e];
        int dl = rec & 255;
        int r = atomicAdd(&lcnt[dl], 1);
        csr[offs[gbase + dl] + r] = rec >> 8;
    }
    __syncthreads();
    int node = gbase + tid;
    if (node < n) {
        int d = lcnt[tid];
        int dp = (d + 3) & ~3;
        int o = offs[node];
        for (int r = d; r < dp; ++r) csr[o + r] = n;   // sentinel (zero row)
    }
}

// zero the sentinel rows of h0/h1
__global__ void k_zrow(float* __restrict__ h0, float* __restrict__ h1, int n) {
    int f = threadIdx.x;
    if (f < H) { h0[(size_t)n * H + f] = 0.f; h1[(size_t)n * H + f] = 0.f; }
}

// ---------------- dense node transforms ----------------

// xwp = (x @ W_gcn) * dinv   (x: [n,64], W: [64,32])
__global__ void k_gemm64s(const float* __restrict__ x, const float* __restrict__ W,
                          const float* __restrict__ dinv, float* __restrict__ xwp, int n) {
    __shared__ float Ws[FIN * H];
    __shared__ float xs[8 * FIN];
    int tid = threadIdx.x;
    for (int i = tid; i < FIN * H; i += 256) Ws[i] = W[i];
    int nodeBase = blockIdx.x * 8;
    for (int i = tid; i < 8 * FIN; i += 256) {
        int node = nodeBase + i / FIN;
        xs[i] = (node < n) ? x[(size_t)node * FIN + (i & 63)] : 0.f;
    }
    __syncthreads();
    int nl = tid >> 5, f = tid & 31;
    int node = nodeBase + nl;
    if (node < n) {
        float acc = 0.f;
        #pragma unroll
        for (int ff = 0; ff < FIN; ++ff) acc += xs[nl * FIN + ff] * Ws[ff * H + f];
        xwp[(size_t)node * H + f] = acc * dinv[node];
    }
}

// GCN: h = relu( dinv[g]*(sum_{s->g} xwp[s] + xwp[g]) + b ), 4-way edge ILP
__global__ void k_gcn(const float* __restrict__ xwp, const int* __restrict__ offs,
                      const int* __restrict__ csr, const float* __restrict__ dinv,
                      const float* __restrict__ bias, float* __restrict__ h, int n) {
    int g = (blockIdx.x * blockDim.x + threadIdx.x) >> 5;
    int f = threadIdx.x & 31;
    if (g >= n) return;
    int s0 = offs[g], s1 = offs[g + 1];
    const int4* cp = (const int4*)(csr + s0);
    int niter = (s1 - s0) >> 2;
    float a0 = 0.f, a1 = 0.f, a2 = 0.f, a3 = 0.f;
    for (int it = 0; it < niter; ++it) {
        int4 s4 = cp[it];
        a0 += xwp[(size_t)s4.x * H + f];
        a1 += xwp[(size_t)s4.y * H + f];
        a2 += xwp[(size_t)s4.z * H + f];
        a3 += xwp[(size_t)s4.w * H + f];
    }
    float acc = (a0 + a1) + (a2 + a3);
    float di = dinv[g];
    float out = di * (acc + xwp[(size_t)g * H + f]) + bias[f];
    h[(size_t)g * H + f] = fmaxf(out, 0.f);
}

// SAGE: hout = relu( mean @ Wl + bl + hin[g] @ Wr ), 4-way edge ILP
__global__ void k_sage(const float* __restrict__ hin, const int* __restrict__ offs,
                       const int* __restrict__ csr, const int* __restrict__ deg,
                       const float* __restrict__ Wl, const float* __restrict__ bl,
                       const float* __restrict__ Wr, float* __restrict__ hout, int n) {
    __shared__ float Wls[H * H], Wrs[H * H];
    int tid = threadIdx.x;
    for (int i = tid; i < H * H; i += 256) { Wls[i] = Wl[i]; Wrs[i] = Wr[i]; }
    __syncthreads();
    int g = (blockIdx.x * blockDim.x + tid) >> 5;
    int f = tid & 31;
    if (g >= n) return;
    int s0 = offs[g], s1 = offs[g + 1];
    const int4* cp = (const int4*)(csr + s0);
    int niter = (s1 - s0) >> 2;
    float a0 = 0.f, a1 = 0.f, a2 = 0.f, a3 = 0.f;
    for (int it = 0; it < niter; ++it) {
        int4 s4 = cp[it];
        a0 += hin[(size_t)s4.x * H + f];
        a1 += hin[(size_t)s4.y * H + f];
        a2 += hin[(size_t)s4.z * H + f];
        a3 += hin[(size_t)s4.w * H + f];
    }
    float mean = ((a0 + a1) + (a2 + a3)) / fmaxf((float)deg[g], 1.f);
    float hf = hin[(size_t)g * H + f];
    float o = bl[f];
    #pragma unroll
    for (int ff = 0; ff < H; ++ff) {
        float mv = __shfl(mean, ff, 32);
        float hv = __shfl(hf, ff, 32);
        o += mv * Wls[ff * H + f] + hv * Wrs[ff * H + f];
    }
    hout[(size_t)g * H + f] = fmaxf(o, 0.f);
}

// ---------------- attention pooling ----------------

__global__ void k_poolsum(const float* __restrict__ rep, const int* __restrict__ batch,
                          float* __restrict__ sums, float* __restrict__ cntg, int n) {
    int g = (blockIdx.x * blockDim.x + threadIdx.x) >> 5;
    int f = threadIdx.x & 31;
    if (g >= n) return;
    int b = batch[g];
    atomicAdd(&sums[b * H + f], rep[(size_t)g * H + f]);
    if (f == 0) atomicAdd(&cntg[b], 1.f);
}

__global__ void k_ctx(const float* __restrict__ sums, const float* __restrict__ cntg,
                      const float* __restrict__ wc, float* __restrict__ ctx, int Bn) {
    int idx = blockIdx.x * blockDim.x + threadIdx.x;
    if (idx >= Bn * H) return;
    int b = idx >> 5, f = idx & 31;
    float inv = 1.f / fmaxf(cntg[b], 1.f);
    float acc = 0.f;
    #pragma unroll
    for (int ff = 0; ff < H; ++ff) acc += sums[b * H + ff] * inv * wc[ff * H + f];
    ctx[idx] = tanhf(acc);
}

__global__ void k_gatepool(const float* __restrict__ rep, const int* __restrict__ batch,
                           const float* __restrict__ ctx, float* __restrict__ pooled, int n) {
    int g = (blockIdx.x * blockDim.x + threadIdx.x) >> 5;
    int f = threadIdx.x & 31;
    if (g >= n) return;
    int b = batch[g];
    float r = rep[(size_t)g * H + f];
    float d = r * ctx[b * H + f];
    #pragma unroll
    for (int m = 16; m >= 1; m >>= 1) d += __shfl_xor(d, m, 32);
    float gate = 1.f / (1.f + expf(-d));
    atomicAdd(&pooled[b * H + f], gate * r);
}

// ---------------- NTN + final MLP ----------------

__global__ void k_ntn(const float* __restrict__ hi, const float* __restrict__ hj,
                      const float* __restrict__ Wntn, const float* __restrict__ Vntn,
                      const float* __restrict__ bntn, const float* __restrict__ mlpw,
                      const float* __restrict__ mlpb, float* __restrict__ out, int Bn) {
    __shared__ float his[8 * H], hjs[8 * H];
    int tid = threadIdx.x;
    int bb = blockIdx.x * 8;
    for (int i = tid; i < 8 * H; i += 256) {
        int b = bb + i / H;
        his[i] = (b < Bn) ? hi[b * H + (i & 31)] : 0.f;
        hjs[i] = (b < Bn) ? hj[b * H + (i & 31)] : 0.f;
    }
    __syncthreads();
    int bl = tid >> 5, k = tid & 31;
    int b = bb + bl;
    if (b >= Bn) return;
    const float* W = Wntn + k * H * H;
    float g = bntn[k];
    #pragma unroll 4
    for (int i = 0; i < H; ++i) {
        float acc = 0.f;
        #pragma unroll
        for (int j = 0; j < H; ++j) acc += W[i * H + j] * hjs[bl * H + j];
        g += his[bl * H + i] * acc;
    }
    const float* V = Vntn + k * 2 * H;
    #pragma unroll
    for (int f = 0; f < H; ++f) g += his[bl * H + f] * V[f] + hjs[bl * H + f] * V[H + f];
    float sc = g * mlpw[k];
    #pragma unroll
    for (int m = 16; m >= 1; m >>= 1) sc += __shfl_xor(sc, m, 32);
    if (k == 0) out[b] = sc + mlpb[0];
}

// ---------------- host orchestration ----------------

extern "C" void kernel_launch(void* const* d_in, const int* in_sizes, int n_in,
                              void* d_out, int out_size, void* d_ws, size_t ws_size,
                              hipStream_t stream) {
    const float* x_i      = (const float*)d_in[0];
    const int*   ei_i     = (const int*)d_in[1];
    const int*   batch_i  = (const int*)d_in[2];
    const float* x_j      = (const float*)d_in[3];
    const int*   ei_j     = (const int*)d_in[4];
    const int*   batch_j  = (const int*)d_in[5];
    const float* W_gcn    = (const float*)d_in[6];
    const float* b_gcn    = (const float*)d_in[7];
    const float* sage_l   = (const float*)d_in[8];
    const float* sage_bl  = (const float*)d_in[9];
    const float* sage_r   = (const float*)d_in[10];
    const float* weight_c = (const float*)d_in[11];
    const float* W_ntn    = (const float*)d_in[12];
    const float* V_ntn    = (const float*)d_in[13];
    const float* b_ntn    = (const float*)d_in[14];
    const float* mlp_w    = (const float*)d_in[15];
    const float* mlp_b    = (const float*)d_in[16];

    const int N = in_sizes[0] / FIN;
    const int E = in_sizes[1] / 2;
    const int B = out_size;
    const int NB = (N + BNODES - 1) / BNODES;   // 391 for N=100000
    const size_t EpadB = ((size_t)E + 4 * (size_t)N + 64) * 4;  // padded CSR bytes
    const size_t hB    = (size_t)(N + 1) * H * 4;               // one h-buffer

    char* p = (char*)d_ws;
    auto alloc = [&](size_t bytes) {
        char* r = p;
        p += (bytes + 255) & ~(size_t)255;
        return r;
    };
    int*   deg      = (int*)alloc((size_t)N * 4);
    float* dinv     = (float*)alloc((size_t)N * 4);
    int*   bcnt     = (int*)alloc((size_t)NB * 4);
    int*   boff     = (int*)alloc((size_t)(NB + 1) * 4);
    int*   gcur     = (int*)alloc((size_t)NB * 4);
    int*   offs     = (int*)alloc((size_t)(N + 1) * 4);
    // barr (scatter staging, padded size) aliases h0: barr dead after k_sort,
    // h0 fully rewritten by k_zrow+k_gemm64s afterwards (stream-ordered).
    char*  regionA  = (char*)alloc(EpadB > hB ? EpadB : hB);
    int*   barr     = (int*)regionA;
    float* h0       = (float*)regionA;
    int*   csr      = (int*)alloc(EpadB);
    float* h1       = (float*)alloc(hB);
    float* sums     = (float*)alloc((size_t)B * H * 4);
    float* cntg     = (float*)alloc((size_t)B * 4);
    float* ctx      = (float*)alloc((size_t)B * H * 4);
    float* pooled_i = (float*)alloc((size_t)B * H * 4);
    float* pooled_j = (float*)alloc((size_t)B * H * 4);

    const int nodeBlocks = (N * 32 + 255) / 256;

    for (int gi = 0; gi < 2; ++gi) {
        const float* x     = gi ? x_j : x_i;
        const int*   ei    = gi ? ei_j : ei_i;
        const int*   batch = gi ? batch_j : batch_i;
        float* pooled      = gi ? pooled_j : pooled_i;
        const int* src = ei;
        const int* dst = ei + E;

        hipMemsetAsync(deg, 0, (size_t)N * 4, stream);
        k_hist<<<(E + 255) / 256, 256, 0, stream>>>(dst, deg, E);
        k_bucket_cnt<<<NB, 256, 0, stream>>>(deg, bcnt, N);
        k_scanb<<<1, 1024, 0, stream>>>(bcnt, boff, gcur, offs, NB, N);
        k_offs<<<NB, 256, 0, stream>>>(deg, boff, offs, dinv, N);
        k_scatter<<<(E + CHUNK - 1) / CHUNK, 256, 0, stream>>>(src, dst, gcur, barr, E, NB);
        k_sort<<<NB, 256, 0, stream>>>(barr, boff, gcur, offs, csr, N);

        k_zrow<<<1, 64, 0, stream>>>(h0, h1, N);
        k_gemm64s<<<(N + 7) / 8, 256, 0, stream>>>(x, W_gcn, dinv, h0, N);
        k_gcn<<<nodeBlocks, 256, 0, stream>>>(h0, offs, csr, dinv, b_gcn, h1, N);
        k_sage<<<nodeBlocks, 256, 0, stream>>>(h1, offs, csr, deg, sage_l, sage_bl, sage_r, h0, N);
        k_sage<<<nodeBlocks, 256, 0, stream>>>(h0, offs, csr, deg, sage_l + H * H, sage_bl + H,
                                               sage_r + H * H, h1, N);

        hipMemsetAsync(sums, 0, (size_t)B * H * 4, stream);
        hipMemsetAsync(cntg, 0, (size_t)B * 4, stream);
        hipMemsetAsync(pooled, 0, (size_t)B * H * 4, stream);
        k_poolsum<<<nodeBlocks, 256, 0, stream>>>(h1, batch, sums, cntg, N);
        k_ctx<<<(B * H + 255) / 256, 256, 0, stream>>>(sums, cntg, weight_c, ctx, B);
        k_gatepool<<<nodeBlocks, 256, 0, stream>>>(h1, batch, ctx, pooled, N);
    }

    k_ntn<<<(B + 7) / 8, 256, 0, stream>>>(pooled_i, pooled_j, W_ntn, V_ntn, b_ntn,
                                           mlp_w, mlp_b, (float*)d_out, B);
}

// Round 5
// 1194.271 us; speedup vs baseline: 4.5120x; 1.3513x over previous
//
#include <hip/hip_runtime.h>

#define H 32
#define FIN 64
#define BNODES 256      // nodes per bucket (dst_local fits 8 bits)
#define NBMAX 512       // max buckets
#define CHUNK 4096      // edges per scatter block
#define PN 32           // nodes per 32-lane group in segmented pooling

// ---------------- degree histogram ----------------

__global__ void k_hist(const int* __restrict__ dst, int* __restrict__ deg, int E) {
    int e = blockIdx.x * blockDim.x + threadIdx.x;
    if (e < E) atomicAdd(&deg[dst[e]], 1);
}

// bucket counts of PADDED degrees: bcnt[b] = sum over nodes of (deg+3)&~3
__global__ void k_bucket_cnt(const int* __restrict__ deg, int* __restrict__ bcnt, int n) {
    __shared__ int s[256];
    int node = blockIdx.x * BNODES + threadIdx.x;
    int d = (node < n) ? deg[node] : 0;
    s[threadIdx.x] = (d + 3) & ~3;
    __syncthreads();
    for (int st = 128; st > 0; st >>= 1) {
        if (threadIdx.x < st) s[threadIdx.x] += s[threadIdx.x + st];
        __syncthreads();
    }
    if (threadIdx.x == 0) bcnt[blockIdx.x] = s[0];
}

// single-block exclusive scan of bucket counts (NB <= 1024); also offs[n] = total
__global__ void k_scanb(const int* __restrict__ bcnt, int* __restrict__ boff,
                        int* __restrict__ gcur, int* __restrict__ offs, int NB, int n) {
    __shared__ int wsum[16];
    __shared__ int wbase[17];
    int tid = threadIdx.x, lane = tid & 63, wid = tid >> 6;
    int v = (tid < NB) ? bcnt[tid] : 0;
    int incl = v;
    #pragma unroll
    for (int d = 1; d < 64; d <<= 1) {
        int t = __shfl_up(incl, d, 64);
        if (lane >= d) incl += t;
    }
    if (lane == 63) wsum[wid] = incl;
    __syncthreads();
    if (tid == 0) {
        int a = 0;
        #pragma unroll
        for (int w = 0; w < 16; ++w) { wbase[w] = a; a += wsum[w]; }
        wbase[16] = a;
    }
    __syncthreads();
    int excl = wbase[wid] + incl - v;
    if (tid < NB) { boff[tid] = excl; gcur[tid] = excl; }
    if (tid == 0) { boff[NB] = wbase[16]; offs[n] = wbase[16]; }
}

// per-bucket: node offsets (padded-degree local scan + bucket base), dinv
__global__ void k_offs(const int* __restrict__ deg, const int* __restrict__ boff,
                       int* __restrict__ offs, float* __restrict__ dinv, int n) {
    __shared__ int wsum[4];
    __shared__ int wbase[4];
    int tid = threadIdx.x, lane = tid & 63, wid = tid >> 6;
    int node = blockIdx.x * BNODES + tid;
    int d = (node < n) ? deg[node] : 0;
    int dp = (d + 3) & ~3;
    int incl = dp;
    #pragma unroll
    for (int s = 1; s < 64; s <<= 1) {
        int t = __shfl_up(incl, s, 64);
        if (lane >= s) incl += t;
    }
    if (lane == 63) wsum[wid] = incl;
    __syncthreads();
    if (tid == 0) {
        int a = 0;
        #pragma unroll
        for (int w = 0; w < 4; ++w) { wbase[w] = a; a += wsum[w]; }
    }
    __syncthreads();
    if (node < n) {
        offs[node] = boff[blockIdx.x] + wbase[wid] + incl - dp;
        dinv[node] = rsqrtf((float)(d + 1));
    }
}

// ---------------- bucket scatter ----------------
// record = (src << 8) | (dst & 255); bucket = dst >> 8

__global__ void k_scatter(const int* __restrict__ src, const int* __restrict__ dst,
                          int* __restrict__ gcur, int* __restrict__ barr, int E, int NB) {
    __shared__ int lcnt[NBMAX];
    __shared__ int lbase[NBMAX];
    __shared__ int recs[CHUNK];
    __shared__ unsigned short rnk[CHUNK];
    __shared__ unsigned short bkt[CHUNK];
    int tid = threadIdx.x;
    for (int i = tid; i < NB; i += 256) lcnt[i] = 0;
    __syncthreads();
    int base = blockIdx.x * CHUNK;
    for (int i = tid; i < CHUNK; i += 256) {
        int e = base + i;
        if (e < E) {
            int d = dst[e];
            int b = d >> 8;
            recs[i] = (src[e] << 8) | (d & 255);
            bkt[i] = (unsigned short)b;
            rnk[i] = (unsigned short)atomicAdd(&lcnt[b], 1);
        }
    }
    __syncthreads();
    for (int b = tid; b < NB; b += 256) {
        int c = lcnt[b];
        lbase[b] = c ? atomicAdd(&gcur[b], c) : 0;
    }
    __syncthreads();
    for (int i = tid; i < CHUNK; i += 256) {
        int e = base + i;
        if (e < E) barr[lbase[bkt[i]] + rnk[i]] = recs[i];
    }
}

// per-bucket sort into exact padded CSR; pad tails with sentinel node n
__global__ void k_sort(const int* __restrict__ barr, const int* __restrict__ boff,
                       const int* __restrict__ gend, const int* __restrict__ offs,
                       int* __restrict__ csr, int n) {
    __shared__ int lcnt[BNODES];
    int tid = threadIdx.x;
    int bk = blockIdx.x;
    lcnt[tid] = 0;
    __syncthreads();
    int e0 = boff[bk], e1 = gend[bk];
    int gbase = bk * BNODES;
    for (int e = e0 + tid; e < e1; e += 256) {
        int rec = barr[e];
        int dl = rec & 255;
        int r = atomicAdd(&lcnt[dl], 1);
        csr[offs[gbase + dl] + r] = rec >> 8;
    }
    __syncthreads();
    int node = gbase + tid;
    if (node < n) {
        int d = lcnt[tid];
        int dp = (d + 3) & ~3;
        int o = offs[node];
        for (int r = d; r < dp; ++r) csr[o + r] = n;   // sentinel (zero row)
    }
}

// zero the sentinel rows of h0/h1
__global__ void k_zrow(float* __restrict__ h0, float* __restrict__ h1, int n) {
    int f = threadIdx.x;
    if (f < H) { h0[(size_t)n * H + f] = 0.f; h1[(size_t)n * H + f] = 0.f; }
}

// ---------------- dense node transforms ----------------

// xwp = (x @ W_gcn) * dinv   (x: [n,64], W: [64,32])
__global__ void k_gemm64s(const float* __restrict__ x, const float* __restrict__ W,
                          const float* __restrict__ dinv, float* __restrict__ xwp, int n) {
    __shared__ float Ws[FIN * H];
    __shared__ float xs[8 * FIN];
    int tid = threadIdx.x;
    for (int i = tid; i < FIN * H; i += 256) Ws[i] = W[i];
    int nodeBase = blockIdx.x * 8;
    for (int i = tid; i < 8 * FIN; i += 256) {
        int node = nodeBase + i / FIN;
        xs[i] = (node < n) ? x[(size_t)node * FIN + (i & 63)] : 0.f;
    }
    __syncthreads();
    int nl = tid >> 5, f = tid & 31;
    int node = nodeBase + nl;
    if (node < n) {
        float acc = 0.f;
        #pragma unroll
        for (int ff = 0; ff < FIN; ++ff) acc += xs[nl * FIN + ff] * Ws[ff * H + f];
        xwp[(size_t)node * H + f] = acc * dinv[node];
    }
}

// GCN: h = relu( dinv[g]*(sum_{s->g} xwp[s] + xwp[g]) + b ), 4-way edge ILP
__global__ void k_gcn(const float* __restrict__ xwp, const int* __restrict__ offs,
                      const int* __restrict__ csr, const float* __restrict__ dinv,
                      const float* __restrict__ bias, float* __restrict__ h, int n) {
    int g = (blockIdx.x * blockDim.x + threadIdx.x) >> 5;
    int f = threadIdx.x & 31;
    if (g >= n) return;
    int s0 = offs[g], s1 = offs[g + 1];
    const int4* cp = (const int4*)(csr + s0);
    int niter = (s1 - s0) >> 2;
    float a0 = 0.f, a1 = 0.f, a2 = 0.f, a3 = 0.f;
    for (int it = 0; it < niter; ++it) {
        int4 s4 = cp[it];
        a0 += xwp[(size_t)s4.x * H + f];
        a1 += xwp[(size_t)s4.y * H + f];
        a2 += xwp[(size_t)s4.z * H + f];
        a3 += xwp[(size_t)s4.w * H + f];
    }
    float acc = (a0 + a1) + (a2 + a3);
    float di = dinv[g];
    float out = di * (acc + xwp[(size_t)g * H + f]) + bias[f];
    h[(size_t)g * H + f] = fmaxf(out, 0.f);
}

// SAGE: hout = relu( mean @ Wl + bl + hin[g] @ Wr ), 4-way edge ILP
__global__ void k_sage(const float* __restrict__ hin, const int* __restrict__ offs,
                       const int* __restrict__ csr, const int* __restrict__ deg,
                       const float* __restrict__ Wl, const float* __restrict__ bl,
                       const float* __restrict__ Wr, float* __restrict__ hout, int n) {
    __shared__ float Wls[H * H], Wrs[H * H];
    int tid = threadIdx.x;
    for (int i = tid; i < H * H; i += 256) { Wls[i] = Wl[i]; Wrs[i] = Wr[i]; }
    __syncthreads();
    int g = (blockIdx.x * blockDim.x + tid) >> 5;
    int f = tid & 31;
    if (g >= n) return;
    int s0 = offs[g], s1 = offs[g + 1];
    const int4* cp = (const int4*)(csr + s0);
    int niter = (s1 - s0) >> 2;
    float a0 = 0.f, a1 = 0.f, a2 = 0.f, a3 = 0.f;
    for (int it = 0; it < niter; ++it) {
        int4 s4 = cp[it];
        a0 += hin[(size_t)s4.x * H + f];
        a1 += hin[(size_t)s4.y * H + f];
        a2 += hin[(size_t)s4.z * H + f];
        a3 += hin[(size_t)s4.w * H + f];
    }
    float mean = ((a0 + a1) + (a2 + a3)) / fmaxf((float)deg[g], 1.f);
    float hf = hin[(size_t)g * H + f];
    float o = bl[f];
    #pragma unroll
    for (int ff = 0; ff < H; ++ff) {
        float mv = __shfl(mean, ff, 32);
        float hv = __shfl(hf, ff, 32);
        o += mv * Wls[ff * H + f] + hv * Wrs[ff * H + f];
    }
    hout[(size_t)g * H + f] = fmaxf(o, 0.f);
}

// ---------------- attention pooling (segmented: batch sorted) ----------------

__global__ void k_poolsum(const float* __restrict__ rep, const int* __restrict__ batch,
                          float* __restrict__ sums, float* __restrict__ cntg, int n) {
    int grp = (blockIdx.x * blockDim.x + threadIdx.x) >> 5;
    int f = threadIdx.x & 31;
    int base = grp * PN;
    if (base >= n) return;
    int end = min(base + PN, n);
    int cur = batch[base];
    float acc = 0.f, cnt = 0.f;
    for (int g = base; g < end; ++g) {
        int b = batch[g];
        if (b != cur) {
            atomicAdd(&sums[cur * H + f], acc);
            if (f == 0) atomicAdd(&cntg[cur], cnt);
            acc = 0.f; cnt = 0.f; cur = b;
        }
        acc += rep[(size_t)g * H + f];
        cnt += 1.f;
    }
    atomicAdd(&sums[cur * H + f], acc);
    if (f == 0) atomicAdd(&cntg[cur], cnt);
}

__global__ void k_ctx(const float* __restrict__ sums, const float* __restrict__ cntg,
                      const float* __restrict__ wc, float* __restrict__ ctx, int Bn) {
    int idx = blockIdx.x * blockDim.x + threadIdx.x;
    if (idx >= Bn * H) return;
    int b = idx >> 5, f = idx & 31;
    float inv = 1.f / fmaxf(cntg[b], 1.f);
    float acc = 0.f;
    #pragma unroll
    for (int ff = 0; ff < H; ++ff) acc += sums[b * H + ff] * inv * wc[ff * H + f];
    ctx[idx] = tanhf(acc);
}

__global__ void k_gatepool(const float* __restrict__ rep, const int* __restrict__ batch,
                           const float* __restrict__ ctx, float* __restrict__ pooled, int n) {
    int grp = (blockIdx.x * blockDim.x + threadIdx.x) >> 5;
    int f = threadIdx.x & 31;
    int base = grp * PN;
    if (base >= n) return;
    int end = min(base + PN, n);
    int cur = batch[base];
    float cv = ctx[cur * H + f];
    float acc = 0.f;
    for (int g = base; g < end; ++g) {
        int b = batch[g];
        if (b != cur) {
            atomicAdd(&pooled[cur * H + f], acc);
            acc = 0.f; cur = b;
            cv = ctx[cur * H + f];
        }
        float r = rep[(size_t)g * H + f];
        float d = r * cv;
        #pragma unroll
        for (int m = 16; m >= 1; m >>= 1) d += __shfl_xor(d, m, 32);
        float gate = 1.f / (1.f + expf(-d));
        acc += gate * r;
    }
    atomicAdd(&pooled[cur * H + f], acc);
}

// ---------------- NTN + final MLP ----------------

__global__ void k_ntn(const float* __restrict__ hi, const float* __restrict__ hj,
                      const float* __restrict__ Wntn, const float* __restrict__ Vntn,
                      const float* __restrict__ bntn, const float* __restrict__ mlpw,
                      const float* __restrict__ mlpb, float* __restrict__ out, int Bn) {
    __shared__ float his[8 * H], hjs[8 * H];
    int tid = threadIdx.x;
    int bb = blockIdx.x * 8;
    for (int i = tid; i < 8 * H; i += 256) {
        int b = bb + i / H;
        his[i] = (b < Bn) ? hi[b * H + (i & 31)] : 0.f;
        hjs[i] = (b < Bn) ? hj[b * H + (i & 31)] : 0.f;
    }
    __syncthreads();
    int bl = tid >> 5, k = tid & 31;
    int b = bb + bl;
    if (b >= Bn) return;
    const float* W = Wntn + k * H * H;
    float g = bntn[k];
    #pragma unroll 4
    for (int i = 0; i < H; ++i) {
        float acc = 0.f;
        #pragma unroll
        for (int j = 0; j < H; ++j) acc += W[i * H + j] * hjs[bl * H + j];
        g += his[bl * H + i] * acc;
    }
    const float* V = Vntn + k * 2 * H;
    #pragma unroll
    for (int f = 0; f < H; ++f) g += his[bl * H + f] * V[f] + hjs[bl * H + f] * V[H + f];
    float sc = g * mlpw[k];
    #pragma unroll
    for (int m = 16; m >= 1; m >>= 1) sc += __shfl_xor(sc, m, 32);
    if (k == 0) out[b] = sc + mlpb[0];
}

// ---------------- host orchestration ----------------

extern "C" void kernel_launch(void* const* d_in, const int* in_sizes, int n_in,
                              void* d_out, int out_size, void* d_ws, size_t ws_size,
                              hipStream_t stream) {
    const float* x_i      = (const float*)d_in[0];
    const int*   ei_i     = (const int*)d_in[1];
    const int*   batch_i  = (const int*)d_in[2];
    const float* x_j      = (const float*)d_in[3];
    const int*   ei_j     = (const int*)d_in[4];
    const int*   batch_j  = (const int*)d_in[5];
    const float* W_gcn    = (const float*)d_in[6];
    const float* b_gcn    = (const float*)d_in[7];
    const float* sage_l   = (const float*)d_in[8];
    const float* sage_bl  = (const float*)d_in[9];
    const float* sage_r   = (const float*)d_in[10];
    const float* weight_c = (const float*)d_in[11];
    const float* W_ntn    = (const float*)d_in[12];
    const float* V_ntn    = (const float*)d_in[13];
    const float* b_ntn    = (const float*)d_in[14];
    const float* mlp_w    = (const float*)d_in[15];
    const float* mlp_b    = (const float*)d_in[16];

    const int N = in_sizes[0] / FIN;
    const int E = in_sizes[1] / 2;
    const int B = out_size;
    const int NB = (N + BNODES - 1) / BNODES;   // 391 for N=100000
    const size_t EpadB = ((size_t)E + 4 * (size_t)N + 64) * 4;  // padded CSR bytes
    const size_t hB    = (size_t)(N + 1) * H * 4;               // one h-buffer

    char* p = (char*)d_ws;
    auto alloc = [&](size_t bytes) {
        char* r = p;
        p += (bytes + 255) & ~(size_t)255;
        return r;
    };
    int*   deg      = (int*)alloc((size_t)N * 4);
    float* dinv     = (float*)alloc((size_t)N * 4);
    int*   bcnt     = (int*)alloc((size_t)NB * 4);
    int*   boff     = (int*)alloc((size_t)(NB + 1) * 4);
    int*   gcur     = (int*)alloc((size_t)NB * 4);
    int*   offs     = (int*)alloc((size_t)(N + 1) * 4);
    // barr (scatter staging, padded size) aliases h0: barr dead after k_sort,
    // h0 fully rewritten by k_zrow+k_gemm64s afterwards (stream-ordered).
    char*  regionA  = (char*)alloc(EpadB > hB ? EpadB : hB);
    int*   barr     = (int*)regionA;
    float* h0       = (float*)regionA;
    int*   csr      = (int*)alloc(EpadB);
    float* h1       = (float*)alloc(hB);
    float* sums     = (float*)alloc((size_t)B * H * 4);
    float* cntg     = (float*)alloc((size_t)B * 4);
    float* ctx      = (float*)alloc((size_t)B * H * 4);
    float* pooled_i = (float*)alloc((size_t)B * H * 4);
    float* pooled_j = (float*)alloc((size_t)B * H * 4);

    const int nodeBlocks = (N * 32 + 255) / 256;
    const int poolBlocks = ((N + PN - 1) / PN * 32 + 255) / 256;

    for (int gi = 0; gi < 2; ++gi) {
        const float* x     = gi ? x_j : x_i;
        const int*   ei    = gi ? ei_j : ei_i;
        const int*   batch = gi ? batch_j : batch_i;
        float* pooled      = gi ? pooled_j : pooled_i;
        const int* src = ei;
        const int* dst = ei + E;

        hipMemsetAsync(deg, 0, (size_t)N * 4, stream);
        k_hist<<<(E + 255) / 256, 256, 0, stream>>>(dst, deg, E);
        k_bucket_cnt<<<NB, 256, 0, stream>>>(deg, bcnt, N);
        k_scanb<<<1, 1024, 0, stream>>>(bcnt, boff, gcur, offs, NB, N);
        k_offs<<<NB, 256, 0, stream>>>(deg, boff, offs, dinv, N);
        k_scatter<<<(E + CHUNK - 1) / CHUNK, 256, 0, stream>>>(src, dst, gcur, barr, E, NB);
        k_sort<<<NB, 256, 0, stream>>>(barr, boff, gcur, offs, csr, N);

        k_zrow<<<1, 64, 0, stream>>>(h0, h1, N);
        k_gemm64s<<<(N + 7) / 8, 256, 0, stream>>>(x, W_gcn, dinv, h0, N);
        k_gcn<<<nodeBlocks, 256, 0, stream>>>(h0, offs, csr, dinv, b_gcn, h1, N);
        k_sage<<<nodeBlocks, 256, 0, stream>>>(h1, offs, csr, deg, sage_l, sage_bl, sage_r, h0, N);
        k_sage<<<nodeBlocks, 256, 0, stream>>>(h0, offs, csr, deg, sage_l + H * H, sage_bl + H,
                                               sage_r + H * H, h1, N);

        hipMemsetAsync(sums, 0, (size_t)B * H * 4, stream);
        hipMemsetAsync(cntg, 0, (size_t)B * 4, stream);
        hipMemsetAsync(pooled, 0, (size_t)B * H * 4, stream);
        k_poolsum<<<poolBlocks, 256, 0, stream>>>(h1, batch, sums, cntg, N);
        k_ctx<<<(B * H + 255) / 256, 256, 0, stream>>>(sums, cntg, weight_c, ctx, B);
        k_gatepool<<<poolBlocks, 256, 0, stream>>>(h1, batch, ctx, pooled, N);
    }

    k_ntn<<<(B + 7) / 8, 256, 0, stream>>>(pooled_i, pooled_j, W_ntn, V_ntn, b_ntn,
                                           mlp_w, mlp_b, (float*)d_out, B);
}

// Round 8
// 999.182 us; speedup vs baseline: 5.3929x; 1.1952x over previous
//
#include <hip/hip_runtime.h>

#define H 32
#define FIN 64
#define BNODES 256      // nodes per bucket (dst_local fits 8 bits)
#define NBMAX 512       // max buckets
#define CHUNK 4096      // edges per scatter block
#define HCHUNK 8192     // edges per bucket-histogram block
#define PN 32           // nodes per 32-lane group in segmented pooling

// ---------------- bucket histogram (LDS) ----------------

__global__ void k_bhist(const int* __restrict__ dst, int* __restrict__ bcnt, int E, int NB) {
    __shared__ int hcnt[NBMAX];
    int tid = threadIdx.x;
    for (int i = tid; i < NB; i += 256) hcnt[i] = 0;
    __syncthreads();
    int base = blockIdx.x * HCHUNK;
    int end = min(base + HCHUNK, E);
    for (int e = base + tid; e < end; e += 256)
        atomicAdd(&hcnt[dst[e] >> 8], 1);
    __syncthreads();
    for (int b = tid; b < NB; b += 256) {
        int c = hcnt[b];
        if (c) atomicAdd(&bcnt[b], c);
    }
}

// single-block exclusive scan of bucket counts (NB <= 1024)
__global__ void k_scanb(const int* __restrict__ bcnt, int* __restrict__ boff,
                        int* __restrict__ gcur, int NB) {
    __shared__ int wsum[16];
    __shared__ int wbase[17];
    int tid = threadIdx.x, lane = tid & 63, wid = tid >> 6;
    int v = (tid < NB) ? bcnt[tid] : 0;
    int incl = v;
    #pragma unroll
    for (int d = 1; d < 64; d <<= 1) {
        int t = __shfl_up(incl, d, 64);
        if (lane >= d) incl += t;
    }
    if (lane == 63) wsum[wid] = incl;
    __syncthreads();
    if (tid == 0) {
        int a = 0;
        #pragma unroll
        for (int w = 0; w < 16; ++w) { wbase[w] = a; a += wsum[w]; }
        wbase[16] = a;
    }
    __syncthreads();
    int excl = wbase[wid] + incl - v;
    if (tid < NB) { boff[tid] = excl; gcur[tid] = excl; }
    if (tid == 0) boff[NB] = wbase[16];
}

// ---------------- bucket scatter ----------------
// record = (src << 8) | (dst & 255); bucket = dst >> 8

__global__ void k_scatter(const int* __restrict__ src, const int* __restrict__ dst,
                          int* __restrict__ gcur, int* __restrict__ barr, int E, int NB) {
    __shared__ int lcnt[NBMAX];
    __shared__ int lbase[NBMAX];
    __shared__ int recs[CHUNK];
    __shared__ unsigned short rnk[CHUNK];
    __shared__ unsigned short bkt[CHUNK];
    int tid = threadIdx.x;
    for (int i = tid; i < NB; i += 256) lcnt[i] = 0;
    __syncthreads();
    int base = blockIdx.x * CHUNK;
    for (int i = tid; i < CHUNK; i += 256) {
        int e = base + i;
        if (e < E) {
            int d = dst[e];
            int b = d >> 8;
            recs[i] = (src[e] << 8) | (d & 255);
            bkt[i] = (unsigned short)b;
            rnk[i] = (unsigned short)atomicAdd(&lcnt[b], 1);
        }
    }
    __syncthreads();
    for (int b = tid; b < NB; b += 256) {
        int c = lcnt[b];
        lbase[b] = c ? atomicAdd(&gcur[b], c) : 0;
    }
    __syncthreads();
    for (int i = tid; i < CHUNK; i += 256) {
        int e = base + i;
        if (e < E) barr[lbase[bkt[i]] + rnk[i]] = recs[i];
    }
}

// ---------------- per-bucket count pass: deg, dinv, local padded offsets ----------------

__global__ void k_cnt(const int* __restrict__ barr, const int* __restrict__ boff,
                      const int* __restrict__ gend, int* __restrict__ deg,
                      float* __restrict__ dinv, int* __restrict__ loc,
                      int* __restrict__ pcnt, int n) {
    __shared__ int lcnt[BNODES];
    __shared__ int wsum[4];
    __shared__ int wbase[4];
    int tid = threadIdx.x, lane = tid & 63, wid = tid >> 6;
    int bk = blockIdx.x;
    lcnt[tid] = 0;
    __syncthreads();
    int e0 = boff[bk], e1 = gend[bk];
    for (int e = e0 + tid; e < e1; e += 256)
        atomicAdd(&lcnt[barr[e] & 255], 1);
    __syncthreads();
    int d = lcnt[tid];
    int dp = (d + 3) & ~3;
    int incl = dp;
    #pragma unroll
    for (int s = 1; s < 64; s <<= 1) {
        int t = __shfl_up(incl, s, 64);
        if (lane >= s) incl += t;
    }
    if (lane == 63) wsum[wid] = incl;
    __syncthreads();
    if (tid == 0) {
        int a = 0;
        #pragma unroll
        for (int w = 0; w < 4; ++w) { wbase[w] = a; a += wsum[w]; }
    }
    __syncthreads();
    int node = bk * BNODES + tid;
    if (node < n) {
        deg[node] = d;
        dinv[node] = rsqrtf((float)(d + 1));
        loc[node] = wbase[wid] + incl - dp;
    }
    if (tid == 255) pcnt[bk] = wbase[3] + incl;
}

// single-block exclusive scan of padded bucket counts
__global__ void k_scanp(const int* __restrict__ pcnt, int* __restrict__ pboff, int NB) {
    __shared__ int wsum[16];
    __shared__ int wbase[16];
    int tid = threadIdx.x, lane = tid & 63, wid = tid >> 6;
    int v = (tid < NB) ? pcnt[tid] : 0;
    int incl = v;
    #pragma unroll
    for (int d = 1; d < 64; d <<= 1) {
        int t = __shfl_up(incl, d, 64);
        if (lane >= d) incl += t;
    }
    if (lane == 63) wsum[wid] = incl;
    __syncthreads();
    if (tid == 0) {
        int a = 0;
        #pragma unroll
        for (int w = 0; w < 16; ++w) { wbase[w] = a; a += wsum[w]; }
    }
    __syncthreads();
    if (tid < NB) pboff[tid] = wbase[wid] + incl - v;
}

// per-bucket fill pass: ranked CSR write + sentinel pad + final offs
__global__ void k_fill(const int* __restrict__ barr, const int* __restrict__ boff,
                       const int* __restrict__ gend, const int* __restrict__ pboff,
                       const int* __restrict__ loc, int* __restrict__ csr,
                       int* __restrict__ offs, int n) {
    __shared__ int lcnt[BNODES];
    __shared__ int lloc[BNODES];
    int tid = threadIdx.x;
    int bk = blockIdx.x;
    int gbase = bk * BNODES;
    int base = pboff[bk];
    int node = gbase + tid;
    lcnt[tid] = 0;
    lloc[tid] = (node < n) ? (base + loc[node]) : 0;
    __syncthreads();
    int e0 = boff[bk], e1 = gend[bk];
    for (int e = e0 + tid; e < e1; e += 256) {
        int rec = barr[e];
        int dl = rec & 255;
        int r = atomicAdd(&lcnt[dl], 1);
        csr[lloc[dl] + r] = rec >> 8;
    }
    __syncthreads();
    if (node < n) {
        int d = lcnt[tid];
        int dp = (d + 3) & ~3;
        int o = lloc[tid];
        offs[node] = o;
        for (int r = d; r < dp; ++r) csr[o + r] = n;   // sentinel (zero row)
    }
}

// zero the sentinel rows of h0/h1
__global__ void k_zrow(float* __restrict__ h0, float* __restrict__ h1, int n) {
    int f = threadIdx.x;
    if (f < H) { h0[(size_t)n * H + f] = 0.f; h1[(size_t)n * H + f] = 0.f; }
}

// ---------------- dense node transforms ----------------

// xwp = (x @ W_gcn) * dinv   (x: [n,64], W: [64,32])
__global__ void k_gemm64s(const float* __restrict__ x, const float* __restrict__ W,
                          const float* __restrict__ dinv, float* __restrict__ xwp, int n) {
    __shared__ float Ws[FIN * H];
    __shared__ float xs[8 * FIN];
    int tid = threadIdx.x;
    for (int i = tid; i < FIN * H; i += 256) Ws[i] = W[i];
    int nodeBase = blockIdx.x * 8;
    for (int i = tid; i < 8 * FIN; i += 256) {
        int node = nodeBase + i / FIN;
        xs[i] = (node < n) ? x[(size_t)node * FIN + (i & 63)] : 0.f;
    }
    __syncthreads();
    int nl = tid >> 5, f = tid & 31;
    int node = nodeBase + nl;
    if (node < n) {
        float acc = 0.f;
        #pragma unroll
        for (int ff = 0; ff < FIN; ++ff) acc += xs[nl * FIN + ff] * Ws[ff * H + f];
        xwp[(size_t)node * H + f] = acc * dinv[node];
    }
}

// GCN: h = relu( dinv[g]*(sum_{s->g} xwp[s] + xwp[g]) + b ), 4-way edge ILP
__global__ void k_gcn(const float* __restrict__ xwp, const int* __restrict__ offs,
                      const int* __restrict__ deg, const int* __restrict__ csr,
                      const float* __restrict__ dinv, const float* __restrict__ bias,
                      float* __restrict__ h, int n) {
    int g = (blockIdx.x * blockDim.x + threadIdx.x) >> 5;
    int f = threadIdx.x & 31;
    if (g >= n) return;
    const int4* cp = (const int4*)(csr + offs[g]);
    int niter = (deg[g] + 3) >> 2;
    float a0 = 0.f, a1 = 0.f, a2 = 0.f, a3 = 0.f;
    for (int it = 0; it < niter; ++it) {
        int4 s4 = cp[it];
        a0 += xwp[(size_t)s4.x * H + f];
        a1 += xwp[(size_t)s4.y * H + f];
        a2 += xwp[(size_t)s4.z * H + f];
        a3 += xwp[(size_t)s4.w * H + f];
    }
    float acc = (a0 + a1) + (a2 + a3);
    float di = dinv[g];
    float out = di * (acc + xwp[(size_t)g * H + f]) + bias[f];
    h[(size_t)g * H + f] = fmaxf(out, 0.f);
}

// SAGE: hout = relu( mean @ Wl + bl + hin[g] @ Wr ), 4-way edge ILP
__global__ void k_sage(const float* __restrict__ hin, const int* __restrict__ offs,
                       const int* __restrict__ deg, const int* __restrict__ csr,
                       const float* __restrict__ Wl, const float* __restrict__ bl,
                       const float* __restrict__ Wr, float* __restrict__ hout, int n) {
    __shared__ float Wls[H * H], Wrs[H * H];
    int tid = threadIdx.x;
    for (int i = tid; i < H * H; i += 256) { Wls[i] = Wl[i]; Wrs[i] = Wr[i]; }
    __syncthreads();
    int g = (blockIdx.x * blockDim.x + tid) >> 5;
    int f = tid & 31;
    if (g >= n) return;
    int d = deg[g];
    const int4* cp = (const int4*)(csr + offs[g]);
    int niter = (d + 3) >> 2;
    float a0 = 0.f, a1 = 0.f, a2 = 0.f, a3 = 0.f;
    for (int it = 0; it < niter; ++it) {
        int4 s4 = cp[it];
        a0 += hin[(size_t)s4.x * H + f];
        a1 += hin[(size_t)s4.y * H + f];
        a2 += hin[(size_t)s4.z * H + f];
        a3 += hin[(size_t)s4.w * H + f];
    }
    float mean = ((a0 + a1) + (a2 + a3)) / fmaxf((float)d, 1.f);
    float hf = hin[(size_t)g * H + f];
    float o = bl[f];
    #pragma unroll
    for (int ff = 0; ff < H; ++ff) {
        float mv = __shfl(mean, ff, 32);
        float hv = __shfl(hf, ff, 32);
        o += mv * Wls[ff * H + f] + hv * Wrs[ff * H + f];
    }
    hout[(size_t)g * H + f] = fmaxf(o, 0.f);
}

// ---------------- attention pooling (segmented: batch sorted) ----------------

__global__ void k_poolsum(const float* __restrict__ rep, const int* __restrict__ batch,
                          float* __restrict__ sums, float* __restrict__ cntg, int n) {
    int grp = (blockIdx.x * blockDim.x + threadIdx.x) >> 5;
    int f = threadIdx.x & 31;
    int base = grp * PN;
    if (base >= n) return;
    int end = min(base + PN, n);
    int cur = batch[base];
    float acc = 0.f, cnt = 0.f;
    for (int g = base; g < end; ++g) {
        int b = batch[g];
        if (b != cur) {
            atomicAdd(&sums[cur * H + f], acc);
            if (f == 0) atomicAdd(&cntg[cur], cnt);
            acc = 0.f; cnt = 0.f; cur = b;
        }
        acc += rep[(size_t)g * H + f];
        cnt += 1.f;
    }
    atomicAdd(&sums[cur * H + f], acc);
    if (f == 0) atomicAdd(&cntg[cur], cnt);
}

__global__ void k_ctx(const float* __restrict__ sums, const float* __restrict__ cntg,
                      const float* __restrict__ wc, float* __restrict__ ctx, int Bn) {
    int idx = blockIdx.x * blockDim.x + threadIdx.x;
    if (idx >= Bn * H) return;
    int b = idx >> 5, f = idx & 31;
    float inv = 1.f / fmaxf(cntg[b], 1.f);
    float acc = 0.f;
    #pragma unroll
    for (int ff = 0; ff < H; ++ff) acc += sums[b * H + ff] * inv * wc[ff * H + f];
    ctx[idx] = tanhf(acc);
}

__global__ void k_gatepool(const float* __restrict__ rep, const int* __restrict__ batch,
                           const float* __restrict__ ctx, float* __restrict__ pooled, int n) {
    int grp = (blockIdx.x * blockDim.x + threadIdx.x) >> 5;
    int f = threadIdx.x & 31;
    int base = grp * PN;
    if (base >= n) return;
    int end = min(base + PN, n);
    int cur = batch[base];
    float cv = ctx[cur * H + f];
    float acc = 0.f;
    for (int g = base; g < end; ++g) {
        int b = batch[g];
        if (b != cur) {
            atomicAdd(&pooled[cur * H + f], acc);
            acc = 0.f; cur = b;
            cv = ctx[cur * H + f];
        }
        float r = rep[(size_t)g * H + f];
        float d = r * cv;
        #pragma unroll
        for (int m = 16; m >= 1; m >>= 1) d += __shfl_xor(d, m, 32);
        float gate = 1.f / (1.f + expf(-d));
        acc += gate * r;
    }
    atomicAdd(&pooled[cur * H + f], acc);
}

// ---------------- NTN + final MLP ----------------

__global__ void k_ntn(const float* __restrict__ hi, const float* __restrict__ hj,
                      const float* __restrict__ Wntn, const float* __restrict__ Vntn,
                      const float* __restrict__ bntn, const float* __restrict__ mlpw,
                      const float* __restrict__ mlpb, float* __restrict__ out, int Bn) {
    __shared__ float his[8 * H], hjs[8 * H];
    int tid = threadIdx.x;
    int bb = blockIdx.x * 8;
    for (int i = tid; i < 8 * H; i += 256) {
        int b = bb + i / H;
        his[i] = (b < Bn) ? hi[b * H + (i & 31)] : 0.f;
        hjs[i] = (b < Bn) ? hj[b * H + (i & 31)] : 0.f;
    }
    __syncthreads();
    int bl = tid >> 5, k = tid & 31;
    int b = bb + bl;
    if (b >= Bn) return;
    const float* W = Wntn + k * H * H;
    float g = bntn[k];
    #pragma unroll 4
    for (int i = 0; i < H; ++i) {
        float acc = 0.f;
        #pragma unroll
        for (int j = 0; j < H; ++j) acc += W[i * H + j] * hjs[bl * H + j];
        g += his[bl * H + i] * acc;
    }
    const float* V = Vntn + k * 2 * H;
    #pragma unroll
    for (int f = 0; f < H; ++f) g += his[bl * H + f] * V[f] + hjs[bl * H + f] * V[H + f];
    float sc = g * mlpw[k];
    #pragma unroll
    for (int m = 16; m >= 1; m >>= 1) sc += __shfl_xor(sc, m, 32);
    if (k == 0) out[b] = sc + mlpb[0];
}

// ---------------- host orchestration ----------------

extern "C" void kernel_launch(void* const* d_in, const int* in_sizes, int n_in,
                              void* d_out, int out_size, void* d_ws, size_t ws_size,
                              hipStream_t stream) {
    const float* x_i      = (const float*)d_in[0];
    const int*   ei_i     = (const int*)d_in[1];
    const int*   batch_i  = (const int*)d_in[2];
    const float* x_j      = (const float*)d_in[3];
    const int*   ei_j     = (const int*)d_in[4];
    const int*   batch_j  = (const int*)d_in[5];
    const float* W_gcn    = (const float*)d_in[6];
    const float* b_gcn    = (const float*)d_in[7];
    const float* sage_l   = (const float*)d_in[8];
    const float* sage_bl  = (const float*)d_in[9];
    const float* sage_r   = (const float*)d_in[10];
    const float* weight_c = (const float*)d_in[11];
    const float* W_ntn    = (const float*)d_in[12];
    const float* V_ntn    = (const float*)d_in[13];
    const float* b_ntn    = (const float*)d_in[14];
    const float* mlp_w    = (const float*)d_in[15];
    const float* mlp_b    = (const float*)d_in[16];

    const int N = in_sizes[0] / FIN;
    const int E = in_sizes[1] / 2;
    const int B = out_size;
    const int NB = (N + BNODES - 1) / BNODES;   // 391 for N=100000
    const size_t EpadB = ((size_t)E + 4 * (size_t)N + 64) * 4;  // padded CSR bytes
    const size_t hB    = (size_t)(N + 1) * H * 4;               // one h-buffer

    char* p = (char*)d_ws;
    auto alloc = [&](size_t bytes) {
        char* r = p;
        p += (bytes + 255) & ~(size_t)255;
        return r;
    };
    int*   deg      = (int*)alloc((size_t)N * 4);
    float* dinv     = (float*)alloc((size_t)N * 4);
    int*   loc      = (int*)alloc((size_t)N * 4);
    int*   bcnt     = (int*)alloc((size_t)NB * 4);
    int*   boff     = (int*)alloc((size_t)(NB + 1) * 4);
    int*   gcur     = (int*)alloc((size_t)NB * 4);
    int*   pcnt     = (int*)alloc((size_t)NB * 4);
    int*   pboff    = (int*)alloc((size_t)NB * 4);
    int*   offs     = (int*)alloc((size_t)N * 4);
    // barr (scatter staging) aliases h0: barr dead after k_fill,
    // h0 fully rewritten by k_zrow+k_gemm64s afterwards (stream-ordered).
    char*  regionA  = (char*)alloc(EpadB > hB ? EpadB : hB);
    int*   barr     = (int*)regionA;
    float* h0       = (float*)regionA;
    int*   csr      = (int*)alloc(EpadB);
    float* h1       = (float*)alloc(hB);
    float* sums     = (float*)alloc((size_t)B * H * 4);
    float* cntg     = (float*)alloc((size_t)B * 4);
    float* ctx      = (float*)alloc((size_t)B * H * 4);
    float* pooled_i = (float*)alloc((size_t)B * H * 4);
    float* pooled_j = (float*)alloc((size_t)B * H * 4);

    const int nodeBlocks = (N * 32 + 255) / 256;
    const int poolBlocks = ((N + PN - 1) / PN * 32 + 255) / 256;

    for (int gi = 0; gi < 2; ++gi) {
        const float* x     = gi ? x_j : x_i;
        const int*   ei    = gi ? ei_j : ei_i;
        const int*   batch = gi ? batch_j : batch_i;
        float* pooled      = gi ? pooled_j : pooled_i;
        const int* src = ei;
        const int* dst = ei + E;

        hipMemsetAsync(bcnt, 0, (size_t)NB * 4, stream);
        k_bhist<<<(E + HCHUNK - 1) / HCHUNK, 256, 0, stream>>>(dst, bcnt, E, NB);
        k_scanb<<<1, 1024, 0, stream>>>(bcnt, boff, gcur, NB);
        k_scatter<<<(E + CHUNK - 1) / CHUNK, 256, 0, stream>>>(src, dst, gcur, barr, E, NB);
        k_cnt<<<NB, 256, 0, stream>>>(barr, boff, gcur, deg, dinv, loc, pcnt, N);
        k_scanp<<<1, 1024, 0, stream>>>(pcnt, pboff, NB);
        k_fill<<<NB, 256, 0, stream>>>(barr, boff, gcur, pboff, loc, csr, offs, N);

        k_zrow<<<1, 64, 0, stream>>>(h0, h1, N);
        k_gemm64s<<<(N + 7) / 8, 256, 0, stream>>>(x, W_gcn, dinv, h0, N);
        k_gcn<<<nodeBlocks, 256, 0, stream>>>(h0, offs, deg, csr, dinv, b_gcn, h1, N);
        k_sage<<<nodeBlocks, 256, 0, stream>>>(h1, offs, deg, csr, sage_l, sage_bl, sage_r, h0, N);
        k_sage<<<nodeBlocks, 256, 0, stream>>>(h0, offs, deg, csr, sage_l + H * H, sage_bl + H,
                                               sage_r + H * H, h1, N);

        hipMemsetAsync(sums, 0, (size_t)B * H * 4, stream);
        hipMemsetAsync(cntg, 0, (size_t)B * 4, stream);
        hipMemsetAsync(pooled, 0, (size_t)B * H * 4, stream);
        k_poolsum<<<poolBlocks, 256, 0, stream>>>(h1, batch, sums, cntg, N);
        k_ctx<<<(B * H + 255) / 256, 256, 0, stream>>>(sums, cntg, weight_c, ctx, B);
        k_gatepool<<<poolBlocks, 256, 0, stream>>>(h1, batch, ctx, pooled, N);
    }

    k_ntn<<<(B + 7) / 8, 256, 0, stream>>>(pooled_i, pooled_j, W_ntn, V_ntn, b_ntn,
                                           mlp_w, mlp_b, (float*)d_out, B);
}

// Round 9
// 965.997 us; speedup vs baseline: 5.5782x; 1.0344x over previous
//
#include <hip/hip_runtime.h>

#define H 32
#define FIN 64
#define BNODES 256      // nodes per bucket (dst_local fits 8 bits)
#define NBMAX 512       // max buckets
#define CHUNK 4096      // edges per scatter block
#define HCHUNK 8192     // edges per bucket-histogram block
#define PN 32           // nodes per 32-lane group in segmented pooling

typedef unsigned short bf16u;

__device__ __forceinline__ float bf2f(bf16u v) {
    unsigned int u = ((unsigned int)v) << 16;
    return __builtin_bit_cast(float, u);
}
__device__ __forceinline__ bf16u f2bf(float f) {
    unsigned int u = __builtin_bit_cast(unsigned int, f);
    u += 0x7FFF + ((u >> 16) & 1);   // round-to-nearest-even
    return (bf16u)(u >> 16);
}

// ---------------- bucket histogram (LDS) ----------------

__global__ void k_bhist(const int* __restrict__ dst, int* __restrict__ bcnt, int E, int NB) {
    __shared__ int hcnt[NBMAX];
    int tid = threadIdx.x;
    for (int i = tid; i < NB; i += 256) hcnt[i] = 0;
    __syncthreads();
    int base = blockIdx.x * HCHUNK;
    int end = min(base + HCHUNK, E);
    for (int e = base + tid; e < end; e += 256)
        atomicAdd(&hcnt[dst[e] >> 8], 1);
    __syncthreads();
    for (int b = tid; b < NB; b += 256) {
        int c = hcnt[b];
        if (c) atomicAdd(&bcnt[b], c);
    }
}

// single-block exclusive scan of bucket counts (NB <= 1024)
__global__ void k_scanb(const int* __restrict__ bcnt, int* __restrict__ boff,
                        int* __restrict__ gcur, int NB) {
    __shared__ int wsum[16];
    __shared__ int wbase[17];
    int tid = threadIdx.x, lane = tid & 63, wid = tid >> 6;
    int v = (tid < NB) ? bcnt[tid] : 0;
    int incl = v;
    #pragma unroll
    for (int d = 1; d < 64; d <<= 1) {
        int t = __shfl_up(incl, d, 64);
        if (lane >= d) incl += t;
    }
    if (lane == 63) wsum[wid] = incl;
    __syncthreads();
    if (tid == 0) {
        int a = 0;
        #pragma unroll
        for (int w = 0; w < 16; ++w) { wbase[w] = a; a += wsum[w]; }
        wbase[16] = a;
    }
    __syncthreads();
    int excl = wbase[wid] + incl - v;
    if (tid < NB) { boff[tid] = excl; gcur[tid] = excl; }
    if (tid == 0) boff[NB] = wbase[16];
}

// ---------------- bucket scatter ----------------
// record = (src << 8) | (dst & 255); bucket = dst >> 8

__global__ void k_scatter(const int* __restrict__ src, const int* __restrict__ dst,
                          int* __restrict__ gcur, int* __restrict__ barr, int E, int NB) {
    __shared__ int lcnt[NBMAX];
    __shared__ int lbase[NBMAX];
    __shared__ int recs[CHUNK];
    __shared__ unsigned short rnk[CHUNK];
    __shared__ unsigned short bkt[CHUNK];
    int tid = threadIdx.x;
    for (int i = tid; i < NB; i += 256) lcnt[i] = 0;
    __syncthreads();
    int base = blockIdx.x * CHUNK;
    for (int i = tid; i < CHUNK; i += 256) {
        int e = base + i;
        if (e < E) {
            int d = dst[e];
            int b = d >> 8;
            recs[i] = (src[e] << 8) | (d & 255);
            bkt[i] = (unsigned short)b;
            rnk[i] = (unsigned short)atomicAdd(&lcnt[b], 1);
        }
    }
    __syncthreads();
    for (int b = tid; b < NB; b += 256) {
        int c = lcnt[b];
        lbase[b] = c ? atomicAdd(&gcur[b], c) : 0;
    }
    __syncthreads();
    for (int i = tid; i < CHUNK; i += 256) {
        int e = base + i;
        if (e < E) barr[lbase[bkt[i]] + rnk[i]] = recs[i];
    }
}

// ---------------- per-bucket count pass: deg, dinv, local padded offsets ----------------

__global__ void k_cnt(const int* __restrict__ barr, const int* __restrict__ boff,
                      const int* __restrict__ gend, int* __restrict__ deg,
                      float* __restrict__ dinv, int* __restrict__ loc,
                      int* __restrict__ pcnt, int n) {
    __shared__ int lcnt[BNODES];
    __shared__ int wsum[4];
    __shared__ int wbase[4];
    int tid = threadIdx.x, lane = tid & 63, wid = tid >> 6;
    int bk = blockIdx.x;
    lcnt[tid] = 0;
    __syncthreads();
    int e0 = boff[bk], e1 = gend[bk];
    for (int e = e0 + tid; e < e1; e += 256)
        atomicAdd(&lcnt[barr[e] & 255], 1);
    __syncthreads();
    int d = lcnt[tid];
    int dp = (d + 3) & ~3;
    int incl = dp;
    #pragma unroll
    for (int s = 1; s < 64; s <<= 1) {
        int t = __shfl_up(incl, s, 64);
        if (lane >= s) incl += t;
    }
    if (lane == 63) wsum[wid] = incl;
    __syncthreads();
    if (tid == 0) {
        int a = 0;
        #pragma unroll
        for (int w = 0; w < 4; ++w) { wbase[w] = a; a += wsum[w]; }
    }
    __syncthreads();
    int node = bk * BNODES + tid;
    if (node < n) {
        deg[node] = d;
        dinv[node] = rsqrtf((float)(d + 1));
        loc[node] = wbase[wid] + incl - dp;
    }
    if (tid == 255) pcnt[bk] = wbase[3] + incl;
}

// single-block exclusive scan of padded bucket counts
__global__ void k_scanp(const int* __restrict__ pcnt, int* __restrict__ pboff, int NB) {
    __shared__ int wsum[16];
    __shared__ int wbase[16];
    int tid = threadIdx.x, lane = tid & 63, wid = tid >> 6;
    int v = (tid < NB) ? pcnt[tid] : 0;
    int incl = v;
    #pragma unroll
    for (int d = 1; d < 64; d <<= 1) {
        int t = __shfl_up(incl, d, 64);
        if (lane >= d) incl += t;
    }
    if (lane == 63) wsum[wid] = incl;
    __syncthreads();
    if (tid == 0) {
        int a = 0;
        #pragma unroll
        for (int w = 0; w < 16; ++w) { wbase[w] = a; a += wsum[w]; }
    }
    __syncthreads();
    if (tid < NB) pboff[tid] = wbase[wid] + incl - v;
}

// per-bucket fill pass: ranked CSR write + sentinel pad + final offs
__global__ void k_fill(const int* __restrict__ barr, const int* __restrict__ boff,
                       const int* __restrict__ gend, const int* __restrict__ pboff,
                       const int* __restrict__ loc, int* __restrict__ csr,
                       int* __restrict__ offs, int n) {
    __shared__ int lcnt[BNODES];
    __shared__ int lloc[BNODES];
    int tid = threadIdx.x;
    int bk = blockIdx.x;
    int gbase = bk * BNODES;
    int base = pboff[bk];
    int node = gbase + tid;
    lcnt[tid] = 0;
    lloc[tid] = (node < n) ? (base + loc[node]) : 0;
    __syncthreads();
    int e0 = boff[bk], e1 = gend[bk];
    for (int e = e0 + tid; e < e1; e += 256) {
        int rec = barr[e];
        int dl = rec & 255;
        int r = atomicAdd(&lcnt[dl], 1);
        csr[lloc[dl] + r] = rec >> 8;
    }
    __syncthreads();
    if (node < n) {
        int d = lcnt[tid];
        int dp = (d + 3) & ~3;
        int o = lloc[tid];
        offs[node] = o;
        for (int r = d; r < dp; ++r) csr[o + r] = n;   // sentinel (zero row)
    }
}

// zero the sentinel rows of h0/h1 (bf16)
__global__ void k_zrow(bf16u* __restrict__ h0, bf16u* __restrict__ h1, int n) {
    int f = threadIdx.x;
    if (f < H) { h0[(size_t)n * H + f] = 0; h1[(size_t)n * H + f] = 0; }
}

// ---------------- dense node transforms ----------------

// xwp = bf16( (x @ W_gcn) * dinv )   (x: [n,64], W: [64,32])
__global__ void k_gemm64s(const float* __restrict__ x, const float* __restrict__ W,
                          const float* __restrict__ dinv, bf16u* __restrict__ xwp, int n) {
    __shared__ float Ws[FIN * H];
    __shared__ float xs[8 * FIN];
    int tid = threadIdx.x;
    for (int i = tid; i < FIN * H; i += 256) Ws[i] = W[i];
    int nodeBase = blockIdx.x * 8;
    for (int i = tid; i < 8 * FIN; i += 256) {
        int node = nodeBase + i / FIN;
        xs[i] = (node < n) ? x[(size_t)node * FIN + (i & 63)] : 0.f;
    }
    __syncthreads();
    int nl = tid >> 5, f = tid & 31;
    int node = nodeBase + nl;
    if (node < n) {
        float acc = 0.f;
        #pragma unroll
        for (int ff = 0; ff < FIN; ++ff) acc += xs[nl * FIN + ff] * Ws[ff * H + f];
        xwp[(size_t)node * H + f] = f2bf(acc * dinv[node]);
    }
}

// GCN: h = relu( dinv[g]*(sum_{s->g} xwp[s] + xwp[g]) + b ), 4-way edge ILP, bf16 rows
__global__ void k_gcn(const bf16u* __restrict__ xwp, const int* __restrict__ offs,
                      const int* __restrict__ deg, const int* __restrict__ csr,
                      const float* __restrict__ dinv, const float* __restrict__ bias,
                      bf16u* __restrict__ h, int n) {
    int g = (blockIdx.x * blockDim.x + threadIdx.x) >> 5;
    int f = threadIdx.x & 31;
    if (g >= n) return;
    const int4* cp = (const int4*)(csr + offs[g]);
    int niter = (deg[g] + 3) >> 2;
    float a0 = 0.f, a1 = 0.f, a2 = 0.f, a3 = 0.f;
    for (int it = 0; it < niter; ++it) {
        int4 s4 = cp[it];
        a0 += bf2f(xwp[(size_t)s4.x * H + f]);
        a1 += bf2f(xwp[(size_t)s4.y * H + f]);
        a2 += bf2f(xwp[(size_t)s4.z * H + f]);
        a3 += bf2f(xwp[(size_t)s4.w * H + f]);
    }
    float acc = (a0 + a1) + (a2 + a3);
    float di = dinv[g];
    float out = di * (acc + bf2f(xwp[(size_t)g * H + f])) + bias[f];
    h[(size_t)g * H + f] = f2bf(fmaxf(out, 0.f));
}

// SAGE: hout = relu( mean @ Wl + bl + hin[g] @ Wr ), 4-way edge ILP, bf16 rows
__global__ void k_sage(const bf16u* __restrict__ hin, const int* __restrict__ offs,
                       const int* __restrict__ deg, const int* __restrict__ csr,
                       const float* __restrict__ Wl, const float* __restrict__ bl,
                       const float* __restrict__ Wr, bf16u* __restrict__ hout, int n) {
    __shared__ float Wls[H * H], Wrs[H * H];
    int tid = threadIdx.x;
    for (int i = tid; i < H * H; i += 256) { Wls[i] = Wl[i]; Wrs[i] = Wr[i]; }
    __syncthreads();
    int g = (blockIdx.x * blockDim.x + tid) >> 5;
    int f = tid & 31;
    if (g >= n) return;
    int d = deg[g];
    const int4* cp = (const int4*)(csr + offs[g]);
    int niter = (d + 3) >> 2;
    float a0 = 0.f, a1 = 0.f, a2 = 0.f, a3 = 0.f;
    for (int it = 0; it < niter; ++it) {
        int4 s4 = cp[it];
        a0 += bf2f(hin[(size_t)s4.x * H + f]);
        a1 += bf2f(hin[(size_t)s4.y * H + f]);
        a2 += bf2f(hin[(size_t)s4.z * H + f]);
        a3 += bf2f(hin[(size_t)s4.w * H + f]);
    }
    float mean = ((a0 + a1) + (a2 + a3)) / fmaxf((float)d, 1.f);
    float hf = bf2f(hin[(size_t)g * H + f]);
    float o = bl[f];
    #pragma unroll
    for (int ff = 0; ff < H; ++ff) {
        float mv = __shfl(mean, ff, 32);
        float hv = __shfl(hf, ff, 32);
        o += mv * Wls[ff * H + f] + hv * Wrs[ff * H + f];
    }
    hout[(size_t)g * H + f] = f2bf(fmaxf(o, 0.f));
}

// ---------------- attention pooling (segmented: batch sorted) ----------------

__global__ void k_poolsum(const bf16u* __restrict__ rep, const int* __restrict__ batch,
                          float* __restrict__ sums, float* __restrict__ cntg, int n) {
    int grp = (blockIdx.x * blockDim.x + threadIdx.x) >> 5;
    int f = threadIdx.x & 31;
    int base = grp * PN;
    if (base >= n) return;
    int end = min(base + PN, n);
    int cur = batch[base];
    float acc = 0.f, cnt = 0.f;
    for (int g = base; g < end; ++g) {
        int b = batch[g];
        if (b != cur) {
            atomicAdd(&sums[cur * H + f], acc);
            if (f == 0) atomicAdd(&cntg[cur], cnt);
            acc = 0.f; cnt = 0.f; cur = b;
        }
        acc += bf2f(rep[(size_t)g * H + f]);
        cnt += 1.f;
    }
    atomicAdd(&sums[cur * H + f], acc);
    if (f == 0) atomicAdd(&cntg[cur], cnt);
}

__global__ void k_ctx(const float* __restrict__ sums, const float* __restrict__ cntg,
                      const float* __restrict__ wc, float* __restrict__ ctx, int Bn) {
    int idx = blockIdx.x * blockDim.x + threadIdx.x;
    if (idx >= Bn * H) return;
    int b = idx >> 5, f = idx & 31;
    float inv = 1.f / fmaxf(cntg[b], 1.f);
    float acc = 0.f;
    #pragma unroll
    for (int ff = 0; ff < H; ++ff) acc += sums[b * H + ff] * inv * wc[ff * H + f];
    ctx[idx] = tanhf(acc);
}

__global__ void k_gatepool(const bf16u* __restrict__ rep, const int* __restrict__ batch,
                           const float* __restrict__ ctx, float* __restrict__ pooled, int n) {
    int grp = (blockIdx.x * blockDim.x + threadIdx.x) >> 5;
    int f = threadIdx.x & 31;
    int base = grp * PN;
    if (base >= n) return;
    int end = min(base + PN, n);
    int cur = batch[base];
    float cv = ctx[cur * H + f];
    float acc = 0.f;
    for (int g = base; g < end; ++g) {
        int b = batch[g];
        if (b != cur) {
            atomicAdd(&pooled[cur * H + f], acc);
            acc = 0.f; cur = b;
            cv = ctx[cur * H + f];
        }
        float r = bf2f(rep[(size_t)g * H + f]);
        float d = r * cv;
        #pragma unroll
        for (int m = 16; m >= 1; m >>= 1) d += __shfl_xor(d, m, 32);
        float gate = 1.f / (1.f + expf(-d));
        acc += gate * r;
    }
    atomicAdd(&pooled[cur * H + f], acc);
}

// ---------------- NTN + final MLP ----------------

__global__ void k_ntn(const float* __restrict__ hi, const float* __restrict__ hj,
                      const float* __restrict__ Wntn, const float* __restrict__ Vntn,
                      const float* __restrict__ bntn, const float* __restrict__ mlpw,
                      const float* __restrict__ mlpb, float* __restrict__ out, int Bn) {
    __shared__ float his[8 * H], hjs[8 * H];
    int tid = threadIdx.x;
    int bb = blockIdx.x * 8;
    for (int i = tid; i < 8 * H; i += 256) {
        int b = bb + i / H;
        his[i] = (b < Bn) ? hi[b * H + (i & 31)] : 0.f;
        hjs[i] = (b < Bn) ? hj[b * H + (i & 31)] : 0.f;
    }
    __syncthreads();
    int bl = tid >> 5, k = tid & 31;
    int b = bb + bl;
    if (b >= Bn) return;
    const float* W = Wntn + k * H * H;
    float g = bntn[k];
    #pragma unroll 4
    for (int i = 0; i < H; ++i) {
        float acc = 0.f;
        #pragma unroll
        for (int j = 0; j < H; ++j) acc += W[i * H + j] * hjs[bl * H + j];
        g += his[bl * H + i] * acc;
    }
    const float* V = Vntn + k * 2 * H;
    #pragma unroll
    for (int f = 0; f < H; ++f) g += his[bl * H + f] * V[f] + hjs[bl * H + f] * V[H + f];
    float sc = g * mlpw[k];
    #pragma unroll
    for (int m = 16; m >= 1; m >>= 1) sc += __shfl_xor(sc, m, 32);
    if (k == 0) out[b] = sc + mlpb[0];
}

// ---------------- host orchestration ----------------

extern "C" void kernel_launch(void* const* d_in, const int* in_sizes, int n_in,
                              void* d_out, int out_size, void* d_ws, size_t ws_size,
                              hipStream_t stream) {
    const float* x_i      = (const float*)d_in[0];
    const int*   ei_i     = (const int*)d_in[1];
    const int*   batch_i  = (const int*)d_in[2];
    const float* x_j      = (const float*)d_in[3];
    const int*   ei_j     = (const int*)d_in[4];
    const int*   batch_j  = (const int*)d_in[5];
    const float* W_gcn    = (const float*)d_in[6];
    const float* b_gcn    = (const float*)d_in[7];
    const float* sage_l   = (const float*)d_in[8];
    const float* sage_bl  = (const float*)d_in[9];
    const float* sage_r   = (const float*)d_in[10];
    const float* weight_c = (const float*)d_in[11];
    const float* W_ntn    = (const float*)d_in[12];
    const float* V_ntn    = (const float*)d_in[13];
    const float* b_ntn    = (const float*)d_in[14];
    const float* mlp_w    = (const float*)d_in[15];
    const float* mlp_b    = (const float*)d_in[16];

    const int N = in_sizes[0] / FIN;
    const int E = in_sizes[1] / 2;
    const int B = out_size;
    const int NB = (N + BNODES - 1) / BNODES;   // 391 for N=100000
    const size_t EpadB = ((size_t)E + 4 * (size_t)N + 64) * 4;  // padded CSR bytes
    const size_t hB    = (size_t)(N + 1) * H * 2;               // one bf16 h-buffer

    char* p = (char*)d_ws;
    auto alloc = [&](size_t bytes) {
        char* r = p;
        p += (bytes + 255) & ~(size_t)255;
        return r;
    };
    int*   deg      = (int*)alloc((size_t)N * 4);
    float* dinv     = (float*)alloc((size_t)N * 4);
    int*   loc      = (int*)alloc((size_t)N * 4);
    int*   bcnt     = (int*)alloc((size_t)NB * 4);
    int*   boff     = (int*)alloc((size_t)(NB + 1) * 4);
    int*   gcur     = (int*)alloc((size_t)NB * 4);
    int*   pcnt     = (int*)alloc((size_t)NB * 4);
    int*   pboff    = (int*)alloc((size_t)NB * 4);
    int*   offs     = (int*)alloc((size_t)N * 4);
    // barr (scatter staging) aliases h0: barr dead after k_fill,
    // h0 fully rewritten by k_zrow+k_gemm64s afterwards (stream-ordered).
    char*  regionA  = (char*)alloc(EpadB > hB ? EpadB : hB);
    int*   barr     = (int*)regionA;
    bf16u* h0       = (bf16u*)regionA;
    int*   csr      = (int*)alloc(EpadB);
    bf16u* h1       = (bf16u*)alloc(hB);
    float* sums     = (float*)alloc((size_t)B * H * 4);
    float* cntg     = (float*)alloc((size_t)B * 4);
    float* ctx      = (float*)alloc((size_t)B * H * 4);
    float* pooled_i = (float*)alloc((size_t)B * H * 4);
    float* pooled_j = (float*)alloc((size_t)B * H * 4);

    const int nodeBlocks = (N * 32 + 255) / 256;
    const int poolBlocks = ((N + PN - 1) / PN * 32 + 255) / 256;

    for (int gi = 0; gi < 2; ++gi) {
        const float* x     = gi ? x_j : x_i;
        const int*   ei    = gi ? ei_j : ei_i;
        const int*   batch = gi ? batch_j : batch_i;
        float* pooled      = gi ? pooled_j : pooled_i;
        const int* src = ei;
        const int* dst = ei + E;

        hipMemsetAsync(bcnt, 0, (size_t)NB * 4, stream);
        k_bhist<<<(E + HCHUNK - 1) / HCHUNK, 256, 0, stream>>>(dst, bcnt, E, NB);
        k_scanb<<<1, 1024, 0, stream>>>(bcnt, boff, gcur, NB);
        k_scatter<<<(E + CHUNK - 1) / CHUNK, 256, 0, stream>>>(src, dst, gcur, barr, E, NB);
        k_cnt<<<NB, 256, 0, stream>>>(barr, boff, gcur, deg, dinv, loc, pcnt, N);
        k_scanp<<<1, 1024, 0, stream>>>(pcnt, pboff, NB);
        k_fill<<<NB, 256, 0, stream>>>(barr, boff, gcur, pboff, loc, csr, offs, N);

        k_zrow<<<1, 64, 0, stream>>>(h0, h1, N);
        k_gemm64s<<<(N + 7) / 8, 256, 0, stream>>>(x, W_gcn, dinv, h0, N);
        k_gcn<<<nodeBlocks, 256, 0, stream>>>(h0, offs, deg, csr, dinv, b_gcn, h1, N);
        k_sage<<<nodeBlocks, 256, 0, stream>>>(h1, offs, deg, csr, sage_l, sage_bl, sage_r, h0, N);
        k_sage<<<nodeBlocks, 256, 0, stream>>>(h0, offs, deg, csr, sage_l + H * H, sage_bl + H,
                                               sage_r + H * H, h1, N);

        hipMemsetAsync(sums, 0, (size_t)B * H * 4, stream);
        hipMemsetAsync(cntg, 0, (size_t)B * 4, stream);
        hipMemsetAsync(pooled, 0, (size_t)B * H * 4, stream);
        k_poolsum<<<poolBlocks, 256, 0, stream>>>(h1, batch, sums, cntg, N);
        k_ctx<<<(B * H + 255) / 256, 256, 0, stream>>>(sums, cntg, weight_c, ctx, B);
        k_gatepool<<<poolBlocks, 256, 0, stream>>>(h1, batch, ctx, pooled, N);
    }

    k_ntn<<<(B + 7) / 8, 256, 0, stream>>>(pooled_i, pooled_j, W_ntn, V_ntn, b_ntn,
                                           mlp_w, mlp_b, (float*)d_out, B);
}

// Round 10
// 837.511 us; speedup vs baseline: 6.4340x; 1.1534x over previous
//
#include <hip/hip_runtime.h>

#define H 32
#define FIN 64
#define BNODES 256      // nodes per bucket (dst_local fits 8 bits)
#define NBMAX 512       // max buckets
#define CHUNK 4096      // edges per scatter block
#define HCHUNK 8192     // edges per bucket-histogram block
#define PN 32           // nodes per 32-lane group in segmented pooling

typedef unsigned short bf16u;

__device__ __forceinline__ float bf2f(bf16u v) {
    unsigned int u = ((unsigned int)v) << 16;
    return __builtin_bit_cast(float, u);
}
__device__ __forceinline__ float bflo(unsigned int u) {
    return __builtin_bit_cast(float, u << 16);
}
__device__ __forceinline__ float bfhi(unsigned int u) {
    return __builtin_bit_cast(float, u & 0xFFFF0000u);
}
__device__ __forceinline__ bf16u f2bf(float f) {
    unsigned int u = __builtin_bit_cast(unsigned int, f);
    u += 0x7FFF + ((u >> 16) & 1);   // round-to-nearest-even
    return (bf16u)(u >> 16);
}
__device__ __forceinline__ unsigned int pack2(float a, float b) {
    return (unsigned int)f2bf(a) | ((unsigned int)f2bf(b) << 16);
}

// ---------------- bucket histogram (LDS) ----------------

__global__ void k_bhist(const int* __restrict__ dst, int* __restrict__ bcnt, int E, int NB) {
    __shared__ int hcnt[NBMAX];
    int tid = threadIdx.x;
    for (int i = tid; i < NB; i += 256) hcnt[i] = 0;
    __syncthreads();
    int base = blockIdx.x * HCHUNK;
    int end = min(base + HCHUNK, E);
    for (int e = base + tid; e < end; e += 256)
        atomicAdd(&hcnt[dst[e] >> 8], 1);
    __syncthreads();
    for (int b = tid; b < NB; b += 256) {
        int c = hcnt[b];
        if (c) atomicAdd(&bcnt[b], c);
    }
}

// single-block exclusive scan of bucket counts (NB <= 1024)
__global__ void k_scanb(const int* __restrict__ bcnt, int* __restrict__ boff,
                        int* __restrict__ gcur, int NB) {
    __shared__ int wsum[16];
    __shared__ int wbase[17];
    int tid = threadIdx.x, lane = tid & 63, wid = tid >> 6;
    int v = (tid < NB) ? bcnt[tid] : 0;
    int incl = v;
    #pragma unroll
    for (int d = 1; d < 64; d <<= 1) {
        int t = __shfl_up(incl, d, 64);
        if (lane >= d) incl += t;
    }
    if (lane == 63) wsum[wid] = incl;
    __syncthreads();
    if (tid == 0) {
        int a = 0;
        #pragma unroll
        for (int w = 0; w < 16; ++w) { wbase[w] = a; a += wsum[w]; }
        wbase[16] = a;
    }
    __syncthreads();
    int excl = wbase[wid] + incl - v;
    if (tid < NB) { boff[tid] = excl; gcur[tid] = excl; }
    if (tid == 0) boff[NB] = wbase[16];
}

// ---------------- bucket scatter ----------------
// record = (src << 8) | (dst & 255); bucket = dst >> 8

__global__ void k_scatter(const int* __restrict__ src, const int* __restrict__ dst,
                          int* __restrict__ gcur, int* __restrict__ barr, int E, int NB) {
    __shared__ int lcnt[NBMAX];
    __shared__ int lbase[NBMAX];
    __shared__ int recs[CHUNK];
    __shared__ unsigned short rnk[CHUNK];
    __shared__ unsigned short bkt[CHUNK];
    int tid = threadIdx.x;
    for (int i = tid; i < NB; i += 256) lcnt[i] = 0;
    __syncthreads();
    int base = blockIdx.x * CHUNK;
    for (int i = tid; i < CHUNK; i += 256) {
        int e = base + i;
        if (e < E) {
            int d = dst[e];
            int b = d >> 8;
            recs[i] = (src[e] << 8) | (d & 255);
            bkt[i] = (unsigned short)b;
            rnk[i] = (unsigned short)atomicAdd(&lcnt[b], 1);
        }
    }
    __syncthreads();
    for (int b = tid; b < NB; b += 256) {
        int c = lcnt[b];
        lbase[b] = c ? atomicAdd(&gcur[b], c) : 0;
    }
    __syncthreads();
    for (int i = tid; i < CHUNK; i += 256) {
        int e = base + i;
        if (e < E) barr[lbase[bkt[i]] + rnk[i]] = recs[i];
    }
}

// ---------------- per-bucket count pass: deg, dinv, local padded offsets ----------------

__global__ void k_cnt(const int* __restrict__ barr, const int* __restrict__ boff,
                      const int* __restrict__ gend, int* __restrict__ deg,
                      float* __restrict__ dinv, int* __restrict__ loc,
                      int* __restrict__ pcnt, int n) {
    __shared__ int lcnt[BNODES];
    __shared__ int wsum[4];
    __shared__ int wbase[4];
    int tid = threadIdx.x, lane = tid & 63, wid = tid >> 6;
    int bk = blockIdx.x;
    lcnt[tid] = 0;
    __syncthreads();
    int e0 = boff[bk], e1 = gend[bk];
    for (int e = e0 + tid; e < e1; e += 256)
        atomicAdd(&lcnt[barr[e] & 255], 1);
    __syncthreads();
    int d = lcnt[tid];
    int dp = (d + 3) & ~3;
    int incl = dp;
    #pragma unroll
    for (int s = 1; s < 64; s <<= 1) {
        int t = __shfl_up(incl, s, 64);
        if (lane >= s) incl += t;
    }
    if (lane == 63) wsum[wid] = incl;
    __syncthreads();
    if (tid == 0) {
        int a = 0;
        #pragma unroll
        for (int w = 0; w < 4; ++w) { wbase[w] = a; a += wsum[w]; }
    }
    __syncthreads();
    int node = bk * BNODES + tid;
    if (node < n) {
        deg[node] = d;
        dinv[node] = rsqrtf((float)(d + 1));
        loc[node] = wbase[wid] + incl - dp;
    }
    if (tid == 255) pcnt[bk] = wbase[3] + incl;
}

// single-block exclusive scan of padded bucket counts
__global__ void k_scanp(const int* __restrict__ pcnt, int* __restrict__ pboff, int NB) {
    __shared__ int wsum[16];
    __shared__ int wbase[16];
    int tid = threadIdx.x, lane = tid & 63, wid = tid >> 6;
    int v = (tid < NB) ? pcnt[tid] : 0;
    int incl = v;
    #pragma unroll
    for (int d = 1; d < 64; d <<= 1) {
        int t = __shfl_up(incl, d, 64);
        if (lane >= d) incl += t;
    }
    if (lane == 63) wsum[wid] = incl;
    __syncthreads();
    if (tid == 0) {
        int a = 0;
        #pragma unroll
        for (int w = 0; w < 16; ++w) { wbase[w] = a; a += wsum[w]; }
    }
    __syncthreads();
    if (tid < NB) pboff[tid] = wbase[wid] + incl - v;
}

// per-bucket fill pass: ranked CSR write + sentinel pad + final offs
__global__ void k_fill(const int* __restrict__ barr, const int* __restrict__ boff,
                       const int* __restrict__ gend, const int* __restrict__ pboff,
                       const int* __restrict__ loc, int* __restrict__ csr,
                       int* __restrict__ offs, int n) {
    __shared__ int lcnt[BNODES];
    __shared__ int lloc[BNODES];
    int tid = threadIdx.x;
    int bk = blockIdx.x;
    int gbase = bk * BNODES;
    int base = pboff[bk];
    int node = gbase + tid;
    lcnt[tid] = 0;
    lloc[tid] = (node < n) ? (base + loc[node]) : 0;
    __syncthreads();
    int e0 = boff[bk], e1 = gend[bk];
    for (int e = e0 + tid; e < e1; e += 256) {
        int rec = barr[e];
        int dl = rec & 255;
        int r = atomicAdd(&lcnt[dl], 1);
        csr[lloc[dl] + r] = rec >> 8;
    }
    __syncthreads();
    if (node < n) {
        int d = lcnt[tid];
        int dp = (d + 3) & ~3;
        int o = lloc[tid];
        offs[node] = o;
        for (int r = d; r < dp; ++r) csr[o + r] = n;   // sentinel (zero row)
    }
}

// zero the sentinel rows of h0/h1 (bf16)
__global__ void k_zrow(bf16u* __restrict__ h0, bf16u* __restrict__ h1, int n) {
    int f = threadIdx.x;
    if (f < H) { h0[(size_t)n * H + f] = 0; h1[(size_t)n * H + f] = 0; }
}

// ---------------- dense node transforms ----------------

// xwp = bf16( (x @ W_gcn) * dinv )   (x: [n,64], W: [64,32])
__global__ void k_gemm64s(const float* __restrict__ x, const float* __restrict__ W,
                          const float* __restrict__ dinv, bf16u* __restrict__ xwp, int n) {
    __shared__ float Ws[FIN * H];
    __shared__ float xs[8 * FIN];
    int tid = threadIdx.x;
    for (int i = tid; i < FIN * H; i += 256) Ws[i] = W[i];
    int nodeBase = blockIdx.x * 8;
    for (int i = tid; i < 8 * FIN; i += 256) {
        int node = nodeBase + i / FIN;
        xs[i] = (node < n) ? x[(size_t)node * FIN + (i & 63)] : 0.f;
    }
    __syncthreads();
    int nl = tid >> 5, f = tid & 31;
    int node = nodeBase + nl;
    if (node < n) {
        float acc = 0.f;
        #pragma unroll
        for (int ff = 0; ff < FIN; ++ff) acc += xs[nl * FIN + ff] * Ws[ff * H + f];
        xwp[(size_t)node * H + f] = f2bf(acc * dinv[node]);
    }
}

// GCN: 16-lane groups, 2 features/lane (dword gathers), 4-way edge ILP + csr prefetch
__global__ void k_gcn(const bf16u* __restrict__ xwp, const int* __restrict__ offs,
                      const int* __restrict__ deg, const int* __restrict__ csr,
                      const float* __restrict__ dinv, const float* __restrict__ bias,
                      bf16u* __restrict__ h, int n) {
    int g = (blockIdx.x * blockDim.x + threadIdx.x) >> 4;
    int f2 = threadIdx.x & 15;
    if (g >= n) return;
    const unsigned int* xw32 = (const unsigned int*)xwp;   // row g at g*16 dwords
    const int4* cp = (const int4*)(csr + offs[g]);
    int niter = (deg[g] + 3) >> 2;
    float a0x = 0.f, a0y = 0.f, a1x = 0.f, a1y = 0.f;
    float a2x = 0.f, a2y = 0.f, a3x = 0.f, a3y = 0.f;
    if (niter > 0) {
        int4 s4 = cp[0];
        for (int it = 0; it < niter; ++it) {
            int4 nxt = (it + 1 < niter) ? cp[it + 1] : s4;
            unsigned int u0 = xw32[(size_t)s4.x * 16 + f2];
            unsigned int u1 = xw32[(size_t)s4.y * 16 + f2];
            unsigned int u2 = xw32[(size_t)s4.z * 16 + f2];
            unsigned int u3 = xw32[(size_t)s4.w * 16 + f2];
            a0x += bflo(u0); a0y += bfhi(u0);
            a1x += bflo(u1); a1y += bfhi(u1);
            a2x += bflo(u2); a2y += bfhi(u2);
            a3x += bflo(u3); a3y += bfhi(u3);
            s4 = nxt;
        }
    }
    float accx = (a0x + a1x) + (a2x + a3x);
    float accy = (a0y + a1y) + (a2y + a3y);
    float di = dinv[g];
    unsigned int ug = xw32[(size_t)g * 16 + f2];
    float ox = di * (accx + bflo(ug)) + bias[2 * f2];
    float oy = di * (accy + bfhi(ug)) + bias[2 * f2 + 1];
    ((unsigned int*)h)[(size_t)g * 16 + f2] = pack2(fmaxf(ox, 0.f), fmaxf(oy, 0.f));
}

// SAGE: 16-lane groups, 2 features/lane, 4-way edge ILP + csr prefetch
__global__ void k_sage(const bf16u* __restrict__ hin, const int* __restrict__ offs,
                       const int* __restrict__ deg, const int* __restrict__ csr,
                       const float* __restrict__ Wl, const float* __restrict__ bl,
                       const float* __restrict__ Wr, bf16u* __restrict__ hout, int n) {
    __shared__ float Wls[H * H], Wrs[H * H];
    int tid = threadIdx.x;
    for (int i = tid; i < H * H; i += 256) { Wls[i] = Wl[i]; Wrs[i] = Wr[i]; }
    __syncthreads();
    int g = (blockIdx.x * blockDim.x + tid) >> 4;
    int f2 = tid & 15;
    if (g >= n) return;
    int d = deg[g];
    const unsigned int* h32 = (const unsigned int*)hin;
    const int4* cp = (const int4*)(csr + offs[g]);
    int niter = (d + 3) >> 2;
    float a0x = 0.f, a0y = 0.f, a1x = 0.f, a1y = 0.f;
    float a2x = 0.f, a2y = 0.f, a3x = 0.f, a3y = 0.f;
    if (niter > 0) {
        int4 s4 = cp[0];
        for (int it = 0; it < niter; ++it) {
            int4 nxt = (it + 1 < niter) ? cp[it + 1] : s4;
            unsigned int u0 = h32[(size_t)s4.x * 16 + f2];
            unsigned int u1 = h32[(size_t)s4.y * 16 + f2];
            unsigned int u2 = h32[(size_t)s4.z * 16 + f2];
            unsigned int u3 = h32[(size_t)s4.w * 16 + f2];
            a0x += bflo(u0); a0y += bfhi(u0);
            a1x += bflo(u1); a1y += bfhi(u1);
            a2x += bflo(u2); a2y += bfhi(u2);
            a3x += bflo(u3); a3y += bfhi(u3);
            s4 = nxt;
        }
    }
    float inv = 1.f / fmaxf((float)d, 1.f);
    float mean0 = ((a0x + a1x) + (a2x + a3x)) * inv;
    float mean1 = ((a0y + a1y) + (a2y + a3y)) * inv;
    unsigned int ug = h32[(size_t)g * 16 + f2];
    float hf0 = bflo(ug), hf1 = bfhi(ug);
    float o0 = bl[2 * f2], o1 = bl[2 * f2 + 1];
    #pragma unroll
    for (int q = 0; q < 16; ++q) {
        float m0 = __shfl(mean0, q, 16);   // feature 2q
        float m1 = __shfl(mean1, q, 16);   // feature 2q+1
        float s0 = __shfl(hf0, q, 16);
        float s1 = __shfl(hf1, q, 16);
        o0 += m0 * Wls[(2 * q) * H + 2 * f2]     + m1 * Wls[(2 * q + 1) * H + 2 * f2]
            + s0 * Wrs[(2 * q) * H + 2 * f2]     + s1 * Wrs[(2 * q + 1) * H + 2 * f2];
        o1 += m0 * Wls[(2 * q) * H + 2 * f2 + 1] + m1 * Wls[(2 * q + 1) * H + 2 * f2 + 1]
            + s0 * Wrs[(2 * q) * H + 2 * f2 + 1] + s1 * Wrs[(2 * q + 1) * H + 2 * f2 + 1];
    }
    ((unsigned int*)hout)[(size_t)g * 16 + f2] = pack2(fmaxf(o0, 0.f), fmaxf(o1, 0.f));
}

// ---------------- attention pooling (segmented: batch sorted) ----------------

__global__ void k_poolsum(const bf16u* __restrict__ rep, const int* __restrict__ batch,
                          float* __restrict__ sums, float* __restrict__ cntg, int n) {
    int grp = (blockIdx.x * blockDim.x + threadIdx.x) >> 5;
    int f = threadIdx.x & 31;
    int base = grp * PN;
    if (base >= n) return;
    int end = min(base + PN, n);
    int cur = batch[base];
    float acc = 0.f, cnt = 0.f;
    for (int g = base; g < end; ++g) {
        int b = batch[g];
        if (b != cur) {
            atomicAdd(&sums[cur * H + f], acc);
            if (f == 0) atomicAdd(&cntg[cur], cnt);
            acc = 0.f; cnt = 0.f; cur = b;
        }
        acc += bf2f(rep[(size_t)g * H + f]);
        cnt += 1.f;
    }
    atomicAdd(&sums[cur * H + f], acc);
    if (f == 0) atomicAdd(&cntg[cur], cnt);
}

__global__ void k_ctx(const float* __restrict__ sums, const float* __restrict__ cntg,
                      const float* __restrict__ wc, float* __restrict__ ctx, int Bn) {
    int idx = blockIdx.x * blockDim.x + threadIdx.x;
    if (idx >= Bn * H) return;
    int b = idx >> 5, f = idx & 31;
    float inv = 1.f / fmaxf(cntg[b], 1.f);
    float acc = 0.f;
    #pragma unroll
    for (int ff = 0; ff < H; ++ff) acc += sums[b * H + ff] * inv * wc[ff * H + f];
    ctx[idx] = tanhf(acc);
}

__global__ void k_gatepool(const bf16u* __restrict__ rep, const int* __restrict__ batch,
                           const float* __restrict__ ctx, float* __restrict__ pooled, int n) {
    int grp = (blockIdx.x * blockDim.x + threadIdx.x) >> 5;
    int f = threadIdx.x & 31;
    int base = grp * PN;
    if (base >= n) return;
    int end = min(base + PN, n);
    int cur = batch[base];
    float cv = ctx[cur * H + f];
    float acc = 0.f;
    for (int g = base; g < end; ++g) {
        int b = batch[g];
        if (b != cur) {
            atomicAdd(&pooled[cur * H + f], acc);
            acc = 0.f; cur = b;
            cv = ctx[cur * H + f];
        }
        float r = bf2f(rep[(size_t)g * H + f]);
        float d = r * cv;
        #pragma unroll
        for (int m = 16; m >= 1; m >>= 1) d += __shfl_xor(d, m, 32);
        float gate = 1.f / (1.f + expf(-d));
        acc += gate * r;
    }
    atomicAdd(&pooled[cur * H + f], acc);
}

// ---------------- NTN + final MLP ----------------

__global__ void k_ntn(const float* __restrict__ hi, const float* __restrict__ hj,
                      const float* __restrict__ Wntn, const float* __restrict__ Vntn,
                      const float* __restrict__ bntn, const float* __restrict__ mlpw,
                      const float* __restrict__ mlpb, float* __restrict__ out, int Bn) {
    __shared__ float his[8 * H], hjs[8 * H];
    int tid = threadIdx.x;
    int bb = blockIdx.x * 8;
    for (int i = tid; i < 8 * H; i += 256) {
        int b = bb + i / H;
        his[i] = (b < Bn) ? hi[b * H + (i & 31)] : 0.f;
        hjs[i] = (b < Bn) ? hj[b * H + (i & 31)] : 0.f;
    }
    __syncthreads();
    int bl = tid >> 5, k = tid & 31;
    int b = bb + bl;
    if (b >= Bn) return;
    const float* W = Wntn + k * H * H;
    float g = bntn[k];
    #pragma unroll 4
    for (int i = 0; i < H; ++i) {
        float acc = 0.f;
        #pragma unroll
        for (int j = 0; j < H; ++j) acc += W[i * H + j] * hjs[bl * H + j];
        g += his[bl * H + i] * acc;
    }
    const float* V = Vntn + k * 2 * H;
    #pragma unroll
    for (int f = 0; f < H; ++f) g += his[bl * H + f] * V[f] + hjs[bl * H + f] * V[H + f];
    float sc = g * mlpw[k];
    #pragma unroll
    for (int m = 16; m >= 1; m >>= 1) sc += __shfl_xor(sc, m, 32);
    if (k == 0) out[b] = sc + mlpb[0];
}

// ---------------- host orchestration ----------------

extern "C" void kernel_launch(void* const* d_in, const int* in_sizes, int n_in,
                              void* d_out, int out_size, void* d_ws, size_t ws_size,
                              hipStream_t stream) {
    const float* x_i      = (const float*)d_in[0];
    const int*   ei_i     = (const int*)d_in[1];
    const int*   batch_i  = (const int*)d_in[2];
    const float* x_j      = (const float*)d_in[3];
    const int*   ei_j     = (const int*)d_in[4];
    const int*   batch_j  = (const int*)d_in[5];
    const float* W_gcn    = (const float*)d_in[6];
    const float* b_gcn    = (const float*)d_in[7];
    const float* sage_l   = (const float*)d_in[8];
    const float* sage_bl  = (const float*)d_in[9];
    const float* sage_r   = (const float*)d_in[10];
    const float* weight_c = (const float*)d_in[11];
    const float* W_ntn    = (const float*)d_in[12];
    const float* V_ntn    = (const float*)d_in[13];
    const float* b_ntn    = (const float*)d_in[14];
    const float* mlp_w    = (const float*)d_in[15];
    const float* mlp_b    = (const float*)d_in[16];

    const int N = in_sizes[0] / FIN;
    const int E = in_sizes[1] / 2;
    const int B = out_size;
    const int NB = (N + BNODES - 1) / BNODES;   // 391 for N=100000
    const size_t EpadB = ((size_t)E + 4 * (size_t)N + 64) * 4;  // padded CSR bytes
    const size_t hB    = (size_t)(N + 1) * H * 2;               // one bf16 h-buffer

    char* p = (char*)d_ws;
    auto alloc = [&](size_t bytes) {
        char* r = p;
        p += (bytes + 255) & ~(size_t)255;
        return r;
    };
    int*   deg      = (int*)alloc((size_t)N * 4);
    float* dinv     = (float*)alloc((size_t)N * 4);
    int*   loc      = (int*)alloc((size_t)N * 4);
    int*   bcnt     = (int*)alloc((size_t)NB * 4);
    int*   boff     = (int*)alloc((size_t)(NB + 1) * 4);
    int*   gcur     = (int*)alloc((size_t)NB * 4);
    int*   pcnt     = (int*)alloc((size_t)NB * 4);
    int*   pboff    = (int*)alloc((size_t)NB * 4);
    int*   offs     = (int*)alloc((size_t)N * 4);
    // barr (scatter staging) aliases h0: barr dead after k_fill,
    // h0 fully rewritten by k_zrow+k_gemm64s afterwards (stream-ordered).
    char*  regionA  = (char*)alloc(EpadB > hB ? EpadB : hB);
    int*   barr     = (int*)regionA;
    bf16u* h0       = (bf16u*)regionA;
    int*   csr      = (int*)alloc(EpadB);
    bf16u* h1       = (bf16u*)alloc(hB);
    float* sums     = (float*)alloc((size_t)B * H * 4);
    float* cntg     = (float*)alloc((size_t)B * 4);
    float* ctx      = (float*)alloc((size_t)B * H * 4);
    float* pooled_i = (float*)alloc((size_t)B * H * 4);
    float* pooled_j = (float*)alloc((size_t)B * H * 4);

    const int convBlocks = (N * 16 + 255) / 256;   // 16 lanes per node
    const int poolBlocks = ((N + PN - 1) / PN * 32 + 255) / 256;

    for (int gi = 0; gi < 2; ++gi) {
        const float* x     = gi ? x_j : x_i;
        const int*   ei    = gi ? ei_j : ei_i;
        const int*   batch = gi ? batch_j : batch_i;
        float* pooled      = gi ? pooled_j : pooled_i;
        const int* src = ei;
        const int* dst = ei + E;

        hipMemsetAsync(bcnt, 0, (size_t)NB * 4, stream);
        k_bhist<<<(E + HCHUNK - 1) / HCHUNK, 256, 0, stream>>>(dst, bcnt, E, NB);
        k_scanb<<<1, 1024, 0, stream>>>(bcnt, boff, gcur, NB);
        k_scatter<<<(E + CHUNK - 1) / CHUNK, 256, 0, stream>>>(src, dst, gcur, barr, E, NB);
        k_cnt<<<NB, 256, 0, stream>>>(barr, boff, gcur, deg, dinv, loc, pcnt, N);
        k_scanp<<<1, 1024, 0, stream>>>(pcnt, pboff, NB);
        k_fill<<<NB, 256, 0, stream>>>(barr, boff, gcur, pboff, loc, csr, offs, N);

        k_zrow<<<1, 64, 0, stream>>>(h0, h1, N);
        k_gemm64s<<<(N + 7) / 8, 256, 0, stream>>>(x, W_gcn, dinv, h0, N);
        k_gcn<<<convBlocks, 256, 0, stream>>>(h0, offs, deg, csr, dinv, b_gcn, h1, N);
        k_sage<<<convBlocks, 256, 0, stream>>>(h1, offs, deg, csr, sage_l, sage_bl, sage_r, h0, N);
        k_sage<<<convBlocks, 256, 0, stream>>>(h0, offs, deg, csr, sage_l + H * H, sage_bl + H,
                                               sage_r + H * H, h1, N);

        hipMemsetAsync(sums, 0, (size_t)B * H * 4, stream);
        hipMemsetAsync(cntg, 0, (size_t)B * 4, stream);
        hipMemsetAsync(pooled, 0, (size_t)B * H * 4, stream);
        k_poolsum<<<poolBlocks, 256, 0, stream>>>(h1, batch, sums, cntg, N);
        k_ctx<<<(B * H + 255) / 256, 256, 0, stream>>>(sums, cntg, weight_c, ctx, B);
        k_gatepool<<<poolBlocks, 256, 0, stream>>>(h1, batch, ctx, pooled, N);
    }

    k_ntn<<<(B + 7) / 8, 256, 0, stream>>>(pooled_i, pooled_j, W_ntn, V_ntn, b_ntn,
                                           mlp_w, mlp_b, (float*)d_out, B);
}

// Round 11
// 659.214 us; speedup vs baseline: 8.1742x; 1.2705x over previous
//
#include <hip/hip_runtime.h>

#define H 32
#define FIN 64
#define BNODES 256      // nodes per bucket (dst_local fits 8 bits)
#define NBMAX 1024      // max buckets (2N/256 = 782)
#define CHUNK 4096      // edges per scatter block
#define HCHUNK 8192     // edges per bucket-histogram block
#define PN 32           // nodes per 32-lane group in segmented pooling

typedef unsigned short bf16u;

__device__ __forceinline__ float bf2f(bf16u v) {
    unsigned int u = ((unsigned int)v) << 16;
    return __builtin_bit_cast(float, u);
}
__device__ __forceinline__ float bflo(unsigned int u) {
    return __builtin_bit_cast(float, u << 16);
}
__device__ __forceinline__ float bfhi(unsigned int u) {
    return __builtin_bit_cast(float, u & 0xFFFF0000u);
}
__device__ __forceinline__ bf16u f2bf(float f) {
    unsigned int u = __builtin_bit_cast(unsigned int, f);
    u += 0x7FFF + ((u >> 16) & 1);   // round-to-nearest-even
    return (bf16u)(u >> 16);
}
__device__ __forceinline__ unsigned int pack2(float a, float b) {
    return (unsigned int)f2bf(a) | ((unsigned int)f2bf(b) << 16);
}

// ---------------- bucket histogram (LDS), node ids offset by `off` ----------------

__global__ void k_bhist(const int* __restrict__ dst, int* __restrict__ bcnt,
                        int E, int NB, int off) {
    __shared__ int hcnt[NBMAX];
    int tid = threadIdx.x;
    for (int i = tid; i < NB; i += 256) hcnt[i] = 0;
    __syncthreads();
    int base = blockIdx.x * HCHUNK;
    int end = min(base + HCHUNK, E);
    for (int e = base + tid; e < end; e += 256)
        atomicAdd(&hcnt[(dst[e] + off) >> 8], 1);
    __syncthreads();
    for (int b = tid; b < NB; b += 256) {
        int c = hcnt[b];
        if (c) atomicAdd(&bcnt[b], c);
    }
}

// single-block exclusive scan of bucket counts (NB <= 1024)
__global__ void k_scanb(const int* __restrict__ bcnt, int* __restrict__ boff,
                        int* __restrict__ gcur, int NB) {
    __shared__ int wsum[16];
    __shared__ int wbase[17];
    int tid = threadIdx.x, lane = tid & 63, wid = tid >> 6;
    int v = (tid < NB) ? bcnt[tid] : 0;
    int incl = v;
    #pragma unroll
    for (int d = 1; d < 64; d <<= 1) {
        int t = __shfl_up(incl, d, 64);
        if (lane >= d) incl += t;
    }
    if (lane == 63) wsum[wid] = incl;
    __syncthreads();
    if (tid == 0) {
        int a = 0;
        #pragma unroll
        for (int w = 0; w < 16; ++w) { wbase[w] = a; a += wsum[w]; }
        wbase[16] = a;
    }
    __syncthreads();
    int excl = wbase[wid] + incl - v;
    if (tid < NB) { boff[tid] = excl; gcur[tid] = excl; }
    if (tid == 0) boff[NB] = wbase[16];
}

// ---------------- bucket scatter (ids offset by `off`) ----------------
// record = ((src+off) << 8) | ((dst+off) & 255); bucket = (dst+off) >> 8

__global__ void k_scatter(const int* __restrict__ src, const int* __restrict__ dst,
                          int* __restrict__ gcur, int* __restrict__ barr,
                          int E, int NB, int off) {
    __shared__ int lcnt[NBMAX];
    __shared__ int lbase[NBMAX];
    __shared__ int recs[CHUNK];
    __shared__ unsigned short rnk[CHUNK];
    __shared__ unsigned short bkt[CHUNK];
    int tid = threadIdx.x;
    for (int i = tid; i < NB; i += 256) lcnt[i] = 0;
    __syncthreads();
    int base = blockIdx.x * CHUNK;
    for (int i = tid; i < CHUNK; i += 256) {
        int e = base + i;
        if (e < E) {
            int d = dst[e] + off;
            int b = d >> 8;
            recs[i] = ((src[e] + off) << 8) | (d & 255);
            bkt[i] = (unsigned short)b;
            rnk[i] = (unsigned short)atomicAdd(&lcnt[b], 1);
        }
    }
    __syncthreads();
    for (int b = tid; b < NB; b += 256) {
        int c = lcnt[b];
        lbase[b] = c ? atomicAdd(&gcur[b], c) : 0;
    }
    __syncthreads();
    for (int i = tid; i < CHUNK; i += 256) {
        int e = base + i;
        if (e < E) barr[lbase[bkt[i]] + rnk[i]] = recs[i];
    }
}

// ---------------- per-bucket count pass: deg, dinv, local pad-8 offsets ----------------

__global__ void k_cnt(const int* __restrict__ barr, const int* __restrict__ boff,
                      const int* __restrict__ gend, int* __restrict__ deg,
                      float* __restrict__ dinv, int* __restrict__ loc,
                      int* __restrict__ pcnt, int n) {
    __shared__ int lcnt[BNODES];
    __shared__ int wsum[4];
    __shared__ int wbase[4];
    int tid = threadIdx.x, lane = tid & 63, wid = tid >> 6;
    int bk = blockIdx.x;
    lcnt[tid] = 0;
    __syncthreads();
    int e0 = boff[bk], e1 = gend[bk];
    for (int e = e0 + tid; e < e1; e += 256)
        atomicAdd(&lcnt[barr[e] & 255], 1);
    __syncthreads();
    int d = lcnt[tid];
    int dp = (d + 7) & ~7;            // pad to 8 for the 8-ILP conv loop
    int incl = dp;
    #pragma unroll
    for (int s = 1; s < 64; s <<= 1) {
        int t = __shfl_up(incl, s, 64);
        if (lane >= s) incl += t;
    }
    if (lane == 63) wsum[wid] = incl;
    __syncthreads();
    if (tid == 0) {
        int a = 0;
        #pragma unroll
        for (int w = 0; w < 4; ++w) { wbase[w] = a; a += wsum[w]; }
    }
    __syncthreads();
    int node = bk * BNODES + tid;
    if (node < n) {
        deg[node] = d;
        dinv[node] = rsqrtf((float)(d + 1));
        loc[node] = wbase[wid] + incl - dp;
    }
    if (tid == 255) pcnt[bk] = wbase[3] + incl;
}

// single-block exclusive scan of padded bucket counts
__global__ void k_scanp(const int* __restrict__ pcnt, int* __restrict__ pboff, int NB) {
    __shared__ int wsum[16];
    __shared__ int wbase[16];
    int tid = threadIdx.x, lane = tid & 63, wid = tid >> 6;
    int v = (tid < NB) ? pcnt[tid] : 0;
    int incl = v;
    #pragma unroll
    for (int d = 1; d < 64; d <<= 1) {
        int t = __shfl_up(incl, d, 64);
        if (lane >= d) incl += t;
    }
    if (lane == 63) wsum[wid] = incl;
    __syncthreads();
    if (tid == 0) {
        int a = 0;
        #pragma unroll
        for (int w = 0; w < 16; ++w) { wbase[w] = a; a += wsum[w]; }
    }
    __syncthreads();
    if (tid < NB) pboff[tid] = wbase[wid] + incl - v;
}

// per-bucket fill pass: ranked CSR write + sentinel pad + final offs
__global__ void k_fill(const int* __restrict__ barr, const int* __restrict__ boff,
                       const int* __restrict__ gend, const int* __restrict__ pboff,
                       const int* __restrict__ loc, int* __restrict__ csr,
                       int* __restrict__ offs, int n) {
    __shared__ int lcnt[BNODES];
    __shared__ int lloc[BNODES];
    int tid = threadIdx.x;
    int bk = blockIdx.x;
    int gbase = bk * BNODES;
    int base = pboff[bk];
    int node = gbase + tid;
    lcnt[tid] = 0;
    lloc[tid] = (node < n) ? (base + loc[node]) : 0;
    __syncthreads();
    int e0 = boff[bk], e1 = gend[bk];
    for (int e = e0 + tid; e < e1; e += 256) {
        int rec = barr[e];
        int dl = rec & 255;
        int r = atomicAdd(&lcnt[dl], 1);
        csr[lloc[dl] + r] = rec >> 8;
    }
    __syncthreads();
    if (node < n) {
        int d = lcnt[tid];
        int dp = (d + 7) & ~7;
        int o = lloc[tid];
        offs[node] = o;
        for (int r = d; r < dp; ++r) csr[o + r] = n;   // sentinel (zero row)
    }
}

// zero the sentinel row of h0/h1 (bf16)
__global__ void k_zrow(bf16u* __restrict__ h0, bf16u* __restrict__ h1, int n) {
    int f = threadIdx.x;
    if (f < H) { h0[(size_t)n * H + f] = 0; h1[(size_t)n * H + f] = 0; }
}

// ---------------- dense node transforms ----------------

// xwp = bf16( (x @ W_gcn) * dinv ), both graphs concatenated
__global__ void k_gemm64s(const float* __restrict__ x1, const float* __restrict__ x2,
                          int n1, const float* __restrict__ W,
                          const float* __restrict__ dinv, bf16u* __restrict__ xwp, int ntot) {
    __shared__ float Ws[FIN * H];
    __shared__ float xs[8 * FIN];
    int tid = threadIdx.x;
    for (int i = tid; i < FIN * H; i += 256) Ws[i] = W[i];
    int nodeBase = blockIdx.x * 8;
    for (int i = tid; i < 8 * FIN; i += 256) {
        int node = nodeBase + i / FIN;
        float v = 0.f;
        if (node < ntot) {
            const float* xr = (node < n1) ? (x1 + (size_t)node * FIN)
                                          : (x2 + (size_t)(node - n1) * FIN);
            v = xr[i & 63];
        }
        xs[i] = v;
    }
    __syncthreads();
    int nl = tid >> 5, f = tid & 31;
    int node = nodeBase + nl;
    if (node < ntot) {
        float acc = 0.f;
        #pragma unroll
        for (int ff = 0; ff < FIN; ++ff) acc += xs[nl * FIN + ff] * Ws[ff * H + f];
        xwp[(size_t)node * H + f] = f2bf(acc * dinv[node]);
    }
}

// GCN: 8-lane groups, 4 features/lane (uint2), 8 gathers in flight
__global__ void k_gcn(const bf16u* __restrict__ xwp, const int* __restrict__ offs,
                      const int* __restrict__ deg, const int* __restrict__ csr,
                      const float* __restrict__ dinv, const float* __restrict__ bias,
                      bf16u* __restrict__ h, int n) {
    int g = (blockIdx.x * blockDim.x + threadIdx.x) >> 3;
    int l = threadIdx.x & 7;
    if (g >= n) return;
    const uint2* x64 = (const uint2*)xwp;   // row g = 8 uint2 at g*8
    const int4* cp = (const int4*)(csr + offs[g]);
    int niter = (deg[g] + 7) >> 3;
    float A0 = 0.f, A1 = 0.f, A2 = 0.f, A3 = 0.f;
    float B0 = 0.f, B1 = 0.f, B2 = 0.f, B3 = 0.f;
    if (niter > 0) {
        int4 qa = cp[0], qb = cp[1];
        for (int it = 0; it < niter; ++it) {
            int4 na = qa, nb = qb;
            if (it + 1 < niter) { na = cp[2 * it + 2]; nb = cp[2 * it + 3]; }
            uint2 u0 = x64[(unsigned)qa.x * 8u + l];
            uint2 u1 = x64[(unsigned)qa.y * 8u + l];
            uint2 u2 = x64[(unsigned)qa.z * 8u + l];
            uint2 u3 = x64[(unsigned)qa.w * 8u + l];
            uint2 u4 = x64[(unsigned)qb.x * 8u + l];
            uint2 u5 = x64[(unsigned)qb.y * 8u + l];
            uint2 u6 = x64[(unsigned)qb.z * 8u + l];
            uint2 u7 = x64[(unsigned)qb.w * 8u + l];
            A0 += bflo(u0.x) + bflo(u1.x) + bflo(u2.x) + bflo(u3.x);
            A1 += bfhi(u0.x) + bfhi(u1.x) + bfhi(u2.x) + bfhi(u3.x);
            A2 += bflo(u0.y) + bflo(u1.y) + bflo(u2.y) + bflo(u3.y);
            A3 += bfhi(u0.y) + bfhi(u1.y) + bfhi(u2.y) + bfhi(u3.y);
            B0 += bflo(u4.x) + bflo(u5.x) + bflo(u6.x) + bflo(u7.x);
            B1 += bfhi(u4.x) + bfhi(u5.x) + bfhi(u6.x) + bfhi(u7.x);
            B2 += bflo(u4.y) + bflo(u5.y) + bflo(u6.y) + bflo(u7.y);
            B3 += bfhi(u4.y) + bfhi(u5.y) + bfhi(u6.y) + bfhi(u7.y);
            qa = na; qb = nb;
        }
    }
    float di = dinv[g];
    uint2 ug = x64[(unsigned)g * 8u + l];
    float o0 = di * (A0 + B0 + bflo(ug.x)) + bias[4 * l + 0];
    float o1 = di * (A1 + B1 + bfhi(ug.x)) + bias[4 * l + 1];
    float o2 = di * (A2 + B2 + bflo(ug.y)) + bias[4 * l + 2];
    float o3 = di * (A3 + B3 + bfhi(ug.y)) + bias[4 * l + 3];
    uint2 outv;
    outv.x = pack2(fmaxf(o0, 0.f), fmaxf(o1, 0.f));
    outv.y = pack2(fmaxf(o2, 0.f), fmaxf(o3, 0.f));
    ((uint2*)h)[(unsigned)g * 8u + l] = outv;
}

// SAGE: 8-lane groups, 4 features/lane, 8 gathers in flight
__global__ void k_sage(const bf16u* __restrict__ hin, const int* __restrict__ offs,
                       const int* __restrict__ deg, const int* __restrict__ csr,
                       const float* __restrict__ Wl, const float* __restrict__ bl,
                       const float* __restrict__ Wr, bf16u* __restrict__ hout, int n) {
    __shared__ float Wls[H * H], Wrs[H * H];
    int tid = threadIdx.x;
    for (int i = tid; i < H * H; i += 256) { Wls[i] = Wl[i]; Wrs[i] = Wr[i]; }
    __syncthreads();
    int g = (blockIdx.x * blockDim.x + tid) >> 3;
    int l = tid & 7;
    if (g >= n) return;
    int d = deg[g];
    const uint2* h64 = (const uint2*)hin;
    const int4* cp = (const int4*)(csr + offs[g]);
    int niter = (d + 7) >> 3;
    float A0 = 0.f, A1 = 0.f, A2 = 0.f, A3 = 0.f;
    float B0 = 0.f, B1 = 0.f, B2 = 0.f, B3 = 0.f;
    if (niter > 0) {
        int4 qa = cp[0], qb = cp[1];
        for (int it = 0; it < niter; ++it) {
            int4 na = qa, nb = qb;
            if (it + 1 < niter) { na = cp[2 * it + 2]; nb = cp[2 * it + 3]; }
            uint2 u0 = h64[(unsigned)qa.x * 8u + l];
            uint2 u1 = h64[(unsigned)qa.y * 8u + l];
            uint2 u2 = h64[(unsigned)qa.z * 8u + l];
            uint2 u3 = h64[(unsigned)qa.w * 8u + l];
            uint2 u4 = h64[(unsigned)qb.x * 8u + l];
            uint2 u5 = h64[(unsigned)qb.y * 8u + l];
            uint2 u6 = h64[(unsigned)qb.z * 8u + l];
            uint2 u7 = h64[(unsigned)qb.w * 8u + l];
            A0 += bflo(u0.x) + bflo(u1.x) + bflo(u2.x) + bflo(u3.x);
            A1 += bfhi(u0.x) + bfhi(u1.x) + bfhi(u2.x) + bfhi(u3.x);
            A2 += bflo(u0.y) + bflo(u1.y) + bflo(u2.y) + bflo(u3.y);
            A3 += bfhi(u0.y) + bfhi(u1.y) + bfhi(u2.y) + bfhi(u3.y);
            B0 += bflo(u4.x) + bflo(u5.x) + bflo(u6.x) + bflo(u7.x);
            B1 += bfhi(u4.x) + bfhi(u5.x) + bfhi(u6.x) + bfhi(u7.x);
            B2 += bflo(u4.y) + bflo(u5.y) + bflo(u6.y) + bflo(u7.y);
            B3 += bfhi(u4.y) + bfhi(u5.y) + bfhi(u6.y) + bfhi(u7.y);
            qa = na; qb = nb;
        }
    }
    float inv = 1.f / fmaxf((float)d, 1.f);
    float m0 = (A0 + B0) * inv, m1 = (A1 + B1) * inv;
    float m2 = (A2 + B2) * inv, m3 = (A3 + B3) * inv;
    uint2 ug = h64[(unsigned)g * 8u + l];
    float s0 = bflo(ug.x), s1 = bfhi(ug.x), s2 = bflo(ug.y), s3 = bfhi(ug.y);
    float o0 = bl[4 * l + 0], o1 = bl[4 * l + 1], o2 = bl[4 * l + 2], o3 = bl[4 * l + 3];
    #pragma unroll
    for (int q = 0; q < 8; ++q) {
        float mm0 = __shfl(m0, q, 8), mm1 = __shfl(m1, q, 8);
        float mm2 = __shfl(m2, q, 8), mm3 = __shfl(m3, q, 8);
        float ss0 = __shfl(s0, q, 8), ss1 = __shfl(s1, q, 8);
        float ss2 = __shfl(s2, q, 8), ss3 = __shfl(s3, q, 8);
        float mm[4] = { mm0, mm1, mm2, mm3 };
        float ss[4] = { ss0, ss1, ss2, ss3 };
        #pragma unroll
        for (int j = 0; j < 4; ++j) {
            float4 wl4 = *(const float4*)&Wls[(4 * q + j) * H + 4 * l];
            float4 wr4 = *(const float4*)&Wrs[(4 * q + j) * H + 4 * l];
            o0 += mm[j] * wl4.x + ss[j] * wr4.x;
            o1 += mm[j] * wl4.y + ss[j] * wr4.y;
            o2 += mm[j] * wl4.z + ss[j] * wr4.z;
            o3 += mm[j] * wl4.w + ss[j] * wr4.w;
        }
    }
    uint2 outv;
    outv.x = pack2(fmaxf(o0, 0.f), fmaxf(o1, 0.f));
    outv.y = pack2(fmaxf(o2, 0.f), fmaxf(o3, 0.f));
    ((uint2*)hout)[(unsigned)g * 8u + l] = outv;
}

// ---------------- attention pooling (segmented; both graphs, batch sorted) ----------------

__global__ void k_poolsum(const bf16u* __restrict__ rep, const int* __restrict__ bi,
                          const int* __restrict__ bj, int n1, int Bn,
                          float* __restrict__ sums, float* __restrict__ cntg, int n) {
    int grp = (blockIdx.x * blockDim.x + threadIdx.x) >> 5;
    int f = threadIdx.x & 31;
    int base = grp * PN;
    if (base >= n) return;
    int end = min(base + PN, n);
    int cur = (base < n1) ? bi[base] : bj[base - n1] + Bn;
    float acc = 0.f, cnt = 0.f;
    for (int g = base; g < end; ++g) {
        int b = (g < n1) ? bi[g] : bj[g - n1] + Bn;
        if (b != cur) {
            atomicAdd(&sums[cur * H + f], acc);
            if (f == 0) atomicAdd(&cntg[cur], cnt);
            acc = 0.f; cnt = 0.f; cur = b;
        }
        acc += bf2f(rep[(size_t)g * H + f]);
        cnt += 1.f;
    }
    atomicAdd(&sums[cur * H + f], acc);
    if (f == 0) atomicAdd(&cntg[cur], cnt);
}

__global__ void k_ctx(const float* __restrict__ sums, const float* __restrict__ cntg,
                      const float* __restrict__ wc, float* __restrict__ ctx, int B2) {
    int idx = blockIdx.x * blockDim.x + threadIdx.x;
    if (idx >= B2 * H) return;
    int b = idx >> 5, f = idx & 31;
    float inv = 1.f / fmaxf(cntg[b], 1.f);
    float acc = 0.f;
    #pragma unroll
    for (int ff = 0; ff < H; ++ff) acc += sums[b * H + ff] * inv * wc[ff * H + f];
    ctx[idx] = tanhf(acc);
}

__global__ void k_gatepool(const bf16u* __restrict__ rep, const int* __restrict__ bi,
                           const int* __restrict__ bj, int n1, int Bn,
                           const float* __restrict__ ctx, float* __restrict__ pooled, int n) {
    int grp = (blockIdx.x * blockDim.x + threadIdx.x) >> 5;
    int f = threadIdx.x & 31;
    int base = grp * PN;
    if (base >= n) return;
    int end = min(base + PN, n);
    int cur = (base < n1) ? bi[base] : bj[base - n1] + Bn;
    float cv = ctx[cur * H + f];
    float acc = 0.f;
    for (int g = base; g < end; ++g) {
        int b = (g < n1) ? bi[g] : bj[g - n1] + Bn;
        if (b != cur) {
            atomicAdd(&pooled[cur * H + f], acc);
            acc = 0.f; cur = b;
            cv = ctx[cur * H + f];
        }
        float r = bf2f(rep[(size_t)g * H + f]);
        float d = r * cv;
        #pragma unroll
        for (int m = 16; m >= 1; m >>= 1) d += __shfl_xor(d, m, 32);
        float gate = 1.f / (1.f + expf(-d));
        acc += gate * r;
    }
    atomicAdd(&pooled[cur * H + f], acc);
}

// ---------------- NTN + final MLP ----------------

__global__ void k_ntn(const float* __restrict__ hi, const float* __restrict__ hj,
                      const float* __restrict__ Wntn, const float* __restrict__ Vntn,
                      const float* __restrict__ bntn, const float* __restrict__ mlpw,
                      const float* __restrict__ mlpb, float* __restrict__ out, int Bn) {
    __shared__ float his[8 * H], hjs[8 * H];
    int tid = threadIdx.x;
    int bb = blockIdx.x * 8;
    for (int i = tid; i < 8 * H; i += 256) {
        int b = bb + i / H;
        his[i] = (b < Bn) ? hi[b * H + (i & 31)] : 0.f;
        hjs[i] = (b < Bn) ? hj[b * H + (i & 31)] : 0.f;
    }
    __syncthreads();
    int bl = tid >> 5, k = tid & 31;
    int b = bb + bl;
    if (b >= Bn) return;
    const float* W = Wntn + k * H * H;
    float g = bntn[k];
    #pragma unroll 4
    for (int i = 0; i < H; ++i) {
        float acc = 0.f;
        #pragma unroll
        for (int j = 0; j < H; ++j) acc += W[i * H + j] * hjs[bl * H + j];
        g += his[bl * H + i] * acc;
    }
    const float* V = Vntn + k * 2 * H;
    #pragma unroll
    for (int f = 0; f < H; ++f) g += his[bl * H + f] * V[f] + hjs[bl * H + f] * V[H + f];
    float sc = g * mlpw[k];
    #pragma unroll
    for (int m = 16; m >= 1; m >>= 1) sc += __shfl_xor(sc, m, 32);
    if (k == 0) out[b] = sc + mlpb[0];
}

// ---------------- host orchestration ----------------

extern "C" void kernel_launch(void* const* d_in, const int* in_sizes, int n_in,
                              void* d_out, int out_size, void* d_ws, size_t ws_size,
                              hipStream_t stream) {
    const float* x_i      = (const float*)d_in[0];
    const int*   ei_i     = (const int*)d_in[1];
    const int*   batch_i  = (const int*)d_in[2];
    const float* x_j      = (const float*)d_in[3];
    const int*   ei_j     = (const int*)d_in[4];
    const int*   batch_j  = (const int*)d_in[5];
    const float* W_gcn    = (const float*)d_in[6];
    const float* b_gcn    = (const float*)d_in[7];
    const float* sage_l   = (const float*)d_in[8];
    const float* sage_bl  = (const float*)d_in[9];
    const float* sage_r   = (const float*)d_in[10];
    const float* weight_c = (const float*)d_in[11];
    const float* W_ntn    = (const float*)d_in[12];
    const float* V_ntn    = (const float*)d_in[13];
    const float* b_ntn    = (const float*)d_in[14];
    const float* mlp_w    = (const float*)d_in[15];
    const float* mlp_b    = (const float*)d_in[16];

    const int N  = in_sizes[0] / FIN;
    const int E  = in_sizes[1] / 2;
    const int B  = out_size;
    const int NT = 2 * N;                      // concatenated node space
    const int NB2 = (NT + BNODES - 1) / BNODES;                 // 782
    const size_t csrB  = ((size_t)2 * E + 8 * (size_t)NT + 64) * 4; // pad-8 CSR bytes
    const size_t barrB = (size_t)2 * E * 4;
    const size_t hB    = (size_t)(NT + 1) * H * 2;              // one bf16 h-buffer

    char* p = (char*)d_ws;
    auto alloc = [&](size_t bytes) {
        char* r = p;
        p += (bytes + 255) & ~(size_t)255;
        return r;
    };
    int*   deg      = (int*)alloc((size_t)NT * 4);
    float* dinv     = (float*)alloc((size_t)NT * 4);
    int*   loc      = (int*)alloc((size_t)NT * 4);
    int*   bcnt     = (int*)alloc((size_t)NB2 * 4);
    int*   boff     = (int*)alloc((size_t)(NB2 + 1) * 4);
    int*   gcur     = (int*)alloc((size_t)NB2 * 4);
    int*   pcnt     = (int*)alloc((size_t)NB2 * 4);
    int*   pboff    = (int*)alloc((size_t)NB2 * 4);
    int*   offs     = (int*)alloc((size_t)NT * 4);
    // barr (scatter staging, 2E ints) aliases h0: barr dead after k_fill,
    // h0 fully rewritten by k_zrow+k_gemm64s afterwards (stream-ordered).
    char*  regionA  = (char*)alloc(barrB > hB ? barrB : hB);
    int*   barr     = (int*)regionA;
    bf16u* h0       = (bf16u*)regionA;
    int*   csr      = (int*)alloc(csrB);
    bf16u* h1       = (bf16u*)alloc(hB);
    float* sums     = (float*)alloc((size_t)2 * B * H * 4);
    float* cntg     = (float*)alloc((size_t)2 * B * 4);
    float* ctx      = (float*)alloc((size_t)2 * B * H * 4);
    float* pooled   = (float*)alloc((size_t)2 * B * H * 4);

    const int convBlocks = (NT * 8 + 255) / 256;    // 8 lanes per node
    const int poolBlocks = ((NT + PN - 1) / PN * 32 + 255) / 256;
    const int histBlocks = (E + HCHUNK - 1) / HCHUNK;
    const int scatBlocks = (E + CHUNK - 1) / CHUNK;

    // ---- fused CSR build over both graphs ----
    hipMemsetAsync(bcnt, 0, (size_t)NB2 * 4, stream);
    k_bhist<<<histBlocks, 256, 0, stream>>>(ei_i + E, bcnt, E, NB2, 0);
    k_bhist<<<histBlocks, 256, 0, stream>>>(ei_j + E, bcnt, E, NB2, N);
    k_scanb<<<1, 1024, 0, stream>>>(bcnt, boff, gcur, NB2);
    k_scatter<<<scatBlocks, 256, 0, stream>>>(ei_i, ei_i + E, gcur, barr, E, NB2, 0);
    k_scatter<<<scatBlocks, 256, 0, stream>>>(ei_j, ei_j + E, gcur, barr, E, NB2, N);
    k_cnt<<<NB2, 256, 0, stream>>>(barr, boff, gcur, deg, dinv, loc, pcnt, NT);
    k_scanp<<<1, 1024, 0, stream>>>(pcnt, pboff, NB2);
    k_fill<<<NB2, 256, 0, stream>>>(barr, boff, gcur, pboff, loc, csr, offs, NT);

    // ---- fused GNN over both graphs ----
    k_zrow<<<1, 64, 0, stream>>>(h0, h1, NT);
    k_gemm64s<<<(NT + 7) / 8, 256, 0, stream>>>(x_i, x_j, N, W_gcn, dinv, h0, NT);
    k_gcn<<<convBlocks, 256, 0, stream>>>(h0, offs, deg, csr, dinv, b_gcn, h1, NT);
    k_sage<<<convBlocks, 256, 0, stream>>>(h1, offs, deg, csr, sage_l, sage_bl, sage_r, h0, NT);
    k_sage<<<convBlocks, 256, 0, stream>>>(h0, offs, deg, csr, sage_l + H * H, sage_bl + H,
                                           sage_r + H * H, h1, NT);

    // ---- fused pooling over both graphs ----
    hipMemsetAsync(sums, 0, (size_t)2 * B * H * 4, stream);
    hipMemsetAsync(cntg, 0, (size_t)2 * B * 4, stream);
    hipMemsetAsync(pooled, 0, (size_t)2 * B * H * 4, stream);
    k_poolsum<<<poolBlocks, 256, 0, stream>>>(h1, batch_i, batch_j, N, B, sums, cntg, NT);
    k_ctx<<<(2 * B * H + 255) / 256, 256, 0, stream>>>(sums, cntg, weight_c, ctx, 2 * B);
    k_gatepool<<<poolBlocks, 256, 0, stream>>>(h1, batch_i, batch_j, N, B, ctx, pooled, NT);

    k_ntn<<<(B + 7) / 8, 256, 0, stream>>>(pooled, pooled + B * H, W_ntn, V_ntn, b_ntn,
                                           mlp_w, mlp_b, (float*)d_out, B);
}